// Round 5
// baseline (358.407 us; speedup 1.0000x reference)
//
#include <hip/hip_runtime.h>

#define N_NODES 100000
#define DIM 16
#define BSHIFT 7
#define BNODES 128                                  // nodes per bucket
#define NB ((N_NODES + BNODES - 1) / BNODES)        // 782 buckets
#define ACC_STRIDE 17                               // LDS pad: kills bank conflicts
#define TB 512
#define SPLIT 4                                     // sub-workgroups per bucket in accum
#define PIPE 8                                      // software-pipeline depth in accum

// ---------------- bucket-sort fast path ----------------

// A: per-workgroup histogram of dst-buckets (LDS atomics only).
__global__ __launch_bounds__(TB) void hist_kernel(const int* __restrict__ dst,
                                                  unsigned* __restrict__ H,
                                                  int E, int chunk) {
    __shared__ unsigned hist[NB];
    int tid = threadIdx.x;
    for (int i = tid; i < NB; i += TB) hist[i] = 0;
    __syncthreads();
    int e0 = blockIdx.x * chunk;
    int e1 = min(e0 + chunk, E);
    for (int e = e0 + tid; e < e1; e += TB)
        atomicAdd(&hist[((unsigned)dst[e]) >> BSHIFT], 1u);
    __syncthreads();
    unsigned* row = H + (size_t)blockIdx.x * NB;
    for (int i = tid; i < NB; i += TB) row[i] = hist[i];
}

// Block-wide exclusive scan (nthreads = TB or 1024, multiple of 64).
__device__ inline unsigned block_scan_excl(unsigned v, int tid, int nthreads,
                                           unsigned* warp_lds, unsigned* total_out) {
    unsigned x = v;
#pragma unroll
    for (int off = 1; off < 64; off <<= 1) {
        unsigned y = __shfl_up(x, off);
        if ((tid & 63) >= off) x += y;
    }
    int wid = tid >> 6;
    int nw = nthreads >> 6;
    if ((tid & 63) == 63) warp_lds[wid] = x;
    __syncthreads();
    if (tid < nw) {
        unsigned w = warp_lds[tid];
#pragma unroll
        for (int off = 1; off < 16; off <<= 1) {
            unsigned y = __shfl_up(w, off);
            if (tid >= off) w += y;
        }
        warp_lds[tid] = w;   // inclusive per-wave totals
    }
    __syncthreads();
    unsigned wbase = (wid > 0) ? warp_lds[wid - 1] : 0u;
    unsigned incl = x + wbase;
    if (total_out && tid == nthreads - 1) *total_out = incl;
    return incl - v;
}

// B1: for each bucket b, exclusive scan of H[wg][b] over wgs (in place) + total.
__global__ __launch_bounds__(TB) void scan_wg_kernel(unsigned* __restrict__ H,
                                                     unsigned* __restrict__ totals,
                                                     int nwg) {
    __shared__ unsigned warp_lds[16];
    int b = blockIdx.x;
    int tid = threadIdx.x;
    unsigned v = (tid < nwg) ? H[(size_t)tid * NB + b] : 0u;
    unsigned excl = block_scan_excl(v, tid, TB, warp_lds, &totals[b]);
    if (tid < nwg) H[(size_t)tid * NB + b] = excl;
}

// B2: exclusive scan of bucket totals -> bucket base offsets.
__global__ __launch_bounds__(1024) void scan_bucket_kernel(const unsigned* __restrict__ totals,
                                                           unsigned* __restrict__ base) {
    __shared__ unsigned warp_lds[16];
    int tid = threadIdx.x;
    unsigned v = (tid < NB) ? totals[tid] : 0u;
    unsigned excl = block_scan_excl(v, tid, 1024, warp_lds, nullptr);
    if (tid < NB) base[tid] = excl;
}

// C: place edge records into bucket-sorted order. LDS atomics for ranks only;
// global writes land in contiguous per-(wg,bucket) runs.
__global__ __launch_bounds__(TB) void place_kernel(const int* __restrict__ src,
                                                   const int* __restrict__ dst,
                                                   const float* __restrict__ probs,
                                                   const unsigned* __restrict__ O,
                                                   const unsigned* __restrict__ base,
                                                   unsigned long long* __restrict__ sorted,
                                                   int E, int chunk) {
    __shared__ unsigned cur[NB];
    int tid = threadIdx.x;
    const unsigned* row = O + (size_t)blockIdx.x * NB;
    for (int i = tid; i < NB; i += TB) cur[i] = base[i] + row[i];
    __syncthreads();
    int e0 = blockIdx.x * chunk;
    int e1 = min(e0 + chunk, E);
    for (int e = e0 + tid; e < e1; e += TB) {
        unsigned d = (unsigned)dst[e];
        unsigned s = (unsigned)src[e];
        float p = probs[e];
        unsigned b = d >> BSHIFT;
        unsigned pos = atomicAdd(&cur[b], 1u);
        unsigned lo = ((d & (BNODES - 1)) << 17) | s;   // src fits 17 bits
        sorted[pos] = ((unsigned long long)__float_as_uint(p) << 32) | lo;
    }
}

// D: persistent grid-stride over (bucket, sub) pairs; 16 lanes per edge.
// 8-deep software pipeline: 8 record loads -> 8 independent x-line gathers ->
// 8 LDS accumulates. Guarded loads (rec=0 => p=0) keep the pipeline branch-free.
__global__ __launch_bounds__(256) void accum_kernel(const float* __restrict__ x,
                                                    const unsigned* __restrict__ base,
                                                    const unsigned* __restrict__ totals,
                                                    const unsigned long long* __restrict__ sorted,
                                                    float* __restrict__ partial,
                                                    int nsub) {
    __shared__ float accs[BNODES * ACC_STRIDE];
    int tid = threadIdx.x;
    int d = tid & 15;           // dim channel
    int slot = tid >> 4;        // 0..15 edge slots per 256-thread pass

    for (int bs = blockIdx.x; bs < nsub; bs += gridDim.x) {
        int b = bs >> 2;        // SPLIT == 4
        int sub = bs & 3;
        for (int i = tid; i < BNODES * ACC_STRIDE; i += 256) accs[i] = 0.0f;
        __syncthreads();

        unsigned s0 = base[b];
        unsigned cnt = totals[b];
        unsigned lo = s0 + (cnt * (unsigned)sub) / SPLIT;
        unsigned hi = s0 + (cnt * (unsigned)(sub + 1)) / SPLIT;

        for (unsigned ibase = lo; ibase < hi; ibase += 16 * PIPE) {
            unsigned long long r[PIPE];
            float v[PIPE];
#pragma unroll
            for (int k = 0; k < PIPE; ++k) {
                unsigned idx = ibase + 16u * k + (unsigned)slot;
                r[k] = (idx < hi) ? sorted[idx] : 0ULL;   // p=0.0f -> contributes 0
            }
#pragma unroll
            for (int k = 0; k < PIPE; ++k) {
                unsigned s = (unsigned)r[k] & 0x1FFFFu;
                v[k] = x[(size_t)s * DIM + d];            // 16 lanes = 1 line
            }
#pragma unroll
            for (int k = 0; k < PIPE; ++k) {
                float p = __uint_as_float((unsigned)(r[k] >> 32));
                unsigned dloc = ((unsigned)r[k] >> 17) & (BNODES - 1);
                atomicAdd(&accs[dloc * ACC_STRIDE + d], v[k] * p);
            }
        }
        __syncthreads();
        float* prow = partial + (size_t)bs * (BNODES * DIM);
        for (int k2 = tid; k2 < BNODES * DIM; k2 += 256)
            prow[k2] = accs[(k2 >> 4) * ACC_STRIDE + (k2 & 15)];
        __syncthreads();   // protect accs before re-zero in next bs iteration
    }
}

// E: reduce SPLIT partials + self-loop + weight + clip -> out.
__global__ __launch_bounds__(256) void finalize_kernel(const float* __restrict__ x,
                                                       const float* __restrict__ weight,
                                                       const float* __restrict__ slw,
                                                       const float* __restrict__ partial,
                                                       float* __restrict__ out) {
    int i = blockIdx.x * 256 + threadIdx.x;   // quad index: node*4 + q
    int n = i >> 2, q = i & 3;
    if (n >= N_NODES) return;
    int b = n >> BSHIFT;
    int nloc = n & (BNODES - 1);
    float4 wv = ((const float4*)weight)[q];
    float4 a = make_float4(0.f, 0.f, 0.f, 0.f);
    size_t pbase = (size_t)(b * SPLIT) * (BNODES * DIM) + (size_t)nloc * DIM + q * 4;
#pragma unroll
    for (int s = 0; s < SPLIT; ++s) {
        float4 pv = *(const float4*)(partial + pbase + (size_t)s * (BNODES * DIM));
        a.x += pv.x; a.y += pv.y; a.z += pv.z; a.w += pv.w;
    }
    float sc = 1.0f + slw[0];
    float4 xv = ((const float4*)x)[i];
    float4 r;
    r.x = fminf(fmaxf(fmaf(xv.x, sc, a.x * wv.x), 0.0f), 1.0f);
    r.y = fminf(fmaxf(fmaf(xv.y, sc, a.y * wv.y), 0.0f), 1.0f);
    r.z = fminf(fmaxf(fmaf(xv.z, sc, a.z * wv.z), 0.0f), 1.0f);
    r.w = fminf(fmaxf(fmaf(xv.w, sc, a.w * wv.w), 0.0f), 1.0f);
    ((float4*)out)[i] = r;
}

// ---------------- fallback path (R1): direct float atomics ----------------

__global__ void diffusion_scatter_kernel(const float* __restrict__ x,
                                         const int* __restrict__ src,
                                         const int* __restrict__ dst,
                                         const float* __restrict__ probs,
                                         const float* __restrict__ weight,
                                         float* __restrict__ acc,
                                         int E) {
    int e = blockIdx.x * blockDim.x + threadIdx.x;
    if (e >= E) return;
    int s = src[e];
    int d = dst[e];
    float p = probs[e];
    const float4* xs = reinterpret_cast<const float4*>(x + (size_t)s * DIM);
    const float4* w4 = reinterpret_cast<const float4*>(weight);
    float* outp = acc + (size_t)d * DIM;
#pragma unroll
    for (int q = 0; q < 4; ++q) {
        float4 xv = xs[q];
        float4 wv = w4[q];
        atomicAdd(&outp[q * 4 + 0], xv.x * p * wv.x);
        atomicAdd(&outp[q * 4 + 1], xv.y * p * wv.y);
        atomicAdd(&outp[q * 4 + 2], xv.z * p * wv.z);
        atomicAdd(&outp[q * 4 + 3], xv.w * p * wv.w);
    }
}

__global__ void diffusion_finalize_kernel(const float* __restrict__ x,
                                          const float* __restrict__ slw,
                                          float* __restrict__ out,
                                          int n4) {
    int i = blockIdx.x * blockDim.x + threadIdx.x;
    if (i >= n4) return;
    float s = 1.0f + slw[0];
    float4 xv = reinterpret_cast<const float4*>(x)[i];
    float4 a = reinterpret_cast<float4*>(out)[i];
    float4 r;
    r.x = fminf(fmaxf(fmaf(xv.x, s, a.x), 0.0f), 1.0f);
    r.y = fminf(fmaxf(fmaf(xv.y, s, a.y), 0.0f), 1.0f);
    r.z = fminf(fmaxf(fmaf(xv.z, s, a.z), 0.0f), 1.0f);
    r.w = fminf(fmaxf(fmaf(xv.w, s, a.w), 0.0f), 1.0f);
    reinterpret_cast<float4*>(out)[i] = r;
}

extern "C" void kernel_launch(void* const* d_in, const int* in_sizes, int n_in,
                              void* d_out, int out_size, void* d_ws, size_t ws_size,
                              hipStream_t stream) {
    const float* x      = (const float*)d_in[0];
    const int*   eidx   = (const int*)d_in[1];   // [2, E]: row0=src, row1=dst
    const float* probs  = (const float*)d_in[2];
    const float* weight = (const float*)d_in[3];
    const float* slw    = (const float*)d_in[4];

    int E = in_sizes[2];
    float* out = (float*)d_out;

    // chunk sizing: keep nwg <= TB so the wg-scan fits one block
    int chunk = (E + TB - 1) / TB;
    if (chunk < 8192) chunk = 8192;
    int nwg = (E + chunk - 1) / chunk;

    // ws layout: H[nwg][NB] | totals[NB] | base[NB] | (align8) sorted[E] u64 | partial
    size_t H_elems = (size_t)nwg * NB;
    size_t head = (H_elems + 2 * (size_t)NB) * sizeof(unsigned);
    head = (head + 7) & ~(size_t)7;
    size_t sorted_bytes = (size_t)E * sizeof(unsigned long long);
    size_t partial_elems = (size_t)NB * SPLIT * BNODES * DIM;
    size_t need = head + sorted_bytes + partial_elems * sizeof(float);

    if (ws_size >= need) {
        unsigned* H = (unsigned*)d_ws;
        unsigned* totals = H + H_elems;
        unsigned* basep = totals + NB;
        unsigned long long* sorted = (unsigned long long*)((char*)d_ws + head);
        float* partial = (float*)((char*)d_ws + head + sorted_bytes);

        hist_kernel<<<nwg, TB, 0, stream>>>(eidx + E, H, E, chunk);
        scan_wg_kernel<<<NB, TB, 0, stream>>>(H, totals, nwg);
        scan_bucket_kernel<<<1, 1024, 0, stream>>>(totals, basep);
        place_kernel<<<nwg, TB, 0, stream>>>(eidx, eidx + E, probs, H, basep,
                                             sorted, E, chunk);
        int nsub = NB * SPLIT;
        accum_kernel<<<2048, 256, 0, stream>>>(x, basep, totals, sorted, partial, nsub);
        int nquad = N_NODES * 4;
        finalize_kernel<<<(nquad + 255) / 256, 256, 0, stream>>>(
            x, weight, slw, partial, out);
    } else {
        const int T = 256;
        hipMemsetAsync(d_out, 0, (size_t)out_size * sizeof(float), stream);
        diffusion_scatter_kernel<<<(E + T - 1) / T, T, 0, stream>>>(
            x, eidx, eidx + E, probs, weight, out, E);
        int n4 = out_size / 4;
        diffusion_finalize_kernel<<<(n4 + T - 1) / T, T, 0, stream>>>(
            x, slw, out, n4);
    }
}

// Round 6
// 142.031 us; speedup vs baseline: 2.5234x; 2.5234x over previous
//
#include <hip/hip_runtime.h>

#define N_NODES 100000
#define DIM 16
#define BSHIFT 7
#define BNODES 128                                  // nodes per bucket
#define NB ((N_NODES + BNODES - 1) / BNODES)        // 782 buckets
#define TB 512

// ---------------- two-level bucket sort + per-node gather ----------------

// A: per-workgroup histogram of dst-buckets (LDS atomics only).
__global__ __launch_bounds__(TB) void hist_kernel(const int* __restrict__ dst,
                                                  unsigned* __restrict__ H,
                                                  int E, int chunk) {
    __shared__ unsigned hist[NB];
    int tid = threadIdx.x;
    for (int i = tid; i < NB; i += TB) hist[i] = 0;
    __syncthreads();
    int e0 = blockIdx.x * chunk;
    int e1 = min(e0 + chunk, E);
    for (int e = e0 + tid; e < e1; e += TB)
        atomicAdd(&hist[((unsigned)dst[e]) >> BSHIFT], 1u);
    __syncthreads();
    unsigned* row = H + (size_t)blockIdx.x * NB;
    for (int i = tid; i < NB; i += TB) row[i] = hist[i];
}

// Block-wide exclusive scan (nthreads = TB or 1024, multiple of 64).
__device__ inline unsigned block_scan_excl(unsigned v, int tid, int nthreads,
                                           unsigned* warp_lds, unsigned* total_out) {
    unsigned x = v;
#pragma unroll
    for (int off = 1; off < 64; off <<= 1) {
        unsigned y = __shfl_up(x, off);
        if ((tid & 63) >= off) x += y;
    }
    int wid = tid >> 6;
    int nw = nthreads >> 6;
    if ((tid & 63) == 63) warp_lds[wid] = x;
    __syncthreads();
    if (tid < nw) {
        unsigned w = warp_lds[tid];
#pragma unroll
        for (int off = 1; off < 16; off <<= 1) {
            unsigned y = __shfl_up(w, off);
            if (tid >= off) w += y;
        }
        warp_lds[tid] = w;   // inclusive per-wave totals
    }
    __syncthreads();
    unsigned wbase = (wid > 0) ? warp_lds[wid - 1] : 0u;
    unsigned incl = x + wbase;
    if (total_out && tid == nthreads - 1) *total_out = incl;
    return incl - v;
}

// B1: for each bucket b, exclusive scan of H[wg][b] over wgs (in place) + total.
__global__ __launch_bounds__(TB) void scan_wg_kernel(unsigned* __restrict__ H,
                                                     unsigned* __restrict__ totals,
                                                     int nwg) {
    __shared__ unsigned warp_lds[16];
    int b = blockIdx.x;
    int tid = threadIdx.x;
    unsigned v = (tid < nwg) ? H[(size_t)tid * NB + b] : 0u;
    unsigned excl = block_scan_excl(v, tid, TB, warp_lds, &totals[b]);
    if (tid < nwg) H[(size_t)tid * NB + b] = excl;
}

// B2: exclusive scan of bucket totals -> bucket base offsets; also base2 sentinel.
__global__ __launch_bounds__(1024) void scan_bucket_kernel(const unsigned* __restrict__ totals,
                                                           unsigned* __restrict__ base,
                                                           unsigned* __restrict__ base2,
                                                           int E) {
    __shared__ unsigned warp_lds[16];
    int tid = threadIdx.x;
    unsigned v = (tid < NB) ? totals[tid] : 0u;
    unsigned excl = block_scan_excl(v, tid, 1024, warp_lds, nullptr);
    if (tid < NB) base[tid] = excl;
    if (tid == 0) base2[N_NODES] = (unsigned)E;
}

// C: place edge records into bucket-sorted order. LDS atomics for ranks only;
// global writes land in contiguous per-(wg,bucket) runs.
__global__ __launch_bounds__(TB) void place_kernel(const int* __restrict__ src,
                                                   const int* __restrict__ dst,
                                                   const float* __restrict__ probs,
                                                   const unsigned* __restrict__ O,
                                                   const unsigned* __restrict__ base,
                                                   unsigned long long* __restrict__ sorted,
                                                   int E, int chunk) {
    __shared__ unsigned cur[NB];
    int tid = threadIdx.x;
    const unsigned* row = O + (size_t)blockIdx.x * NB;
    for (int i = tid; i < NB; i += TB) cur[i] = base[i] + row[i];
    __syncthreads();
    int e0 = blockIdx.x * chunk;
    int e1 = min(e0 + chunk, E);
    for (int e = e0 + tid; e < e1; e += TB) {
        unsigned d = (unsigned)dst[e];
        unsigned s = (unsigned)src[e];
        float p = probs[e];
        unsigned b = d >> BSHIFT;
        unsigned pos = atomicAdd(&cur[b], 1u);
        unsigned lo = ((d & (BNODES - 1)) << 17) | s;   // src fits 17 bits
        sorted[pos] = ((unsigned long long)__float_as_uint(p) << 32) | lo;
    }
}

// D: one wg per bucket — sort the bucket's records to node granularity.
// Pass 1: 128-bin LDS histogram; wave-0 scan; write per-node global offsets.
// Pass 2: re-read records, place at node-sorted positions in sorted2.
__global__ __launch_bounds__(256) void node_sort_kernel(const unsigned* __restrict__ base,
                                                        const unsigned* __restrict__ totals,
                                                        const unsigned long long* __restrict__ sorted,
                                                        unsigned long long* __restrict__ sorted2,
                                                        unsigned* __restrict__ base2) {
    __shared__ unsigned ncnt[BNODES];
    __shared__ unsigned nbase[BNODES];
    int tid = threadIdx.x;
    int b = blockIdx.x;
    unsigned s0 = base[b];
    unsigned s1 = s0 + totals[b];
    if (tid < BNODES) ncnt[tid] = 0;
    __syncthreads();
#pragma unroll 4
    for (unsigned i = s0 + tid; i < s1; i += 256) {
        unsigned dloc = ((unsigned)sorted[i] >> 17) & (BNODES - 1);
        atomicAdd(&ncnt[dloc], 1u);
    }
    __syncthreads();
    // exclusive scan of 128 bins by wave 0 (2 bins per lane)
    if (tid < 64) {
        unsigned c0 = ncnt[2 * tid], c1 = ncnt[2 * tid + 1];
        unsigned v = c0 + c1;
        unsigned xs = v;
#pragma unroll
        for (int off = 1; off < 64; off <<= 1) {
            unsigned y = __shfl_up(xs, off);
            if (tid >= off) xs += y;
        }
        nbase[2 * tid]     = xs - v;    // exclusive for bin 2t
        nbase[2 * tid + 1] = xs - c1;   // exclusive for bin 2t+1
    }
    __syncthreads();
    if (tid < BNODES) {
        int n = b * BNODES + tid;
        if (n < N_NODES) base2[n] = s0 + nbase[tid];
    }
    __syncthreads();
#pragma unroll 4
    for (unsigned i = s0 + tid; i < s1; i += 256) {
        unsigned long long rec = sorted[i];
        unsigned dloc = ((unsigned)rec >> 17) & (BNODES - 1);
        unsigned pos = s0 + atomicAdd(&nbase[dloc], 1u);
        sorted2[pos] = rec;
    }
}

// E: one wave per node over its contiguous record segment. Register
// accumulation, shfl reduce, fused self-loop + weight + clip.
__global__ __launch_bounds__(256) void gather2_kernel(const float* __restrict__ x,
                                                      const float* __restrict__ weight,
                                                      const float* __restrict__ slw,
                                                      const unsigned* __restrict__ base2,
                                                      const unsigned long long* __restrict__ sorted2,
                                                      float* __restrict__ out) {
    int wave = (int)((blockIdx.x * (size_t)blockDim.x + threadIdx.x) >> 6);
    int lane = threadIdx.x & 63;
    if (wave >= N_NODES) return;
    int n = wave;
    unsigned lo = base2[n];
    unsigned hi = base2[n + 1];
    int sub = lane >> 4;   // record sub-slot 0..3
    int dch = lane & 15;   // dim channel
    float acc = 0.0f;
    unsigned i = lo + (unsigned)sub;
    // 2-deep: 8 records in flight per wave
    for (; i + 4 < hi; i += 8) {
        unsigned long long r0 = sorted2[i];
        unsigned long long r1 = sorted2[i + 4];
        unsigned s0_ = (unsigned)r0 & 0x1FFFFu;
        unsigned s1_ = (unsigned)r1 & 0x1FFFFu;
        float v0 = x[(size_t)s0_ * DIM + dch];
        float v1 = x[(size_t)s1_ * DIM + dch];
        acc = fmaf(v0, __uint_as_float((unsigned)(r0 >> 32)), acc);
        acc = fmaf(v1, __uint_as_float((unsigned)(r1 >> 32)), acc);
    }
    for (; i < hi; i += 4) {
        unsigned long long r0 = sorted2[i];
        unsigned s0_ = (unsigned)r0 & 0x1FFFFu;
        acc = fmaf(x[(size_t)s0_ * DIM + dch],
                   __uint_as_float((unsigned)(r0 >> 32)), acc);
    }
    acc += __shfl_xor(acc, 16);
    acc += __shfl_xor(acc, 32);
    if (lane < 16) {
        float xv = x[(size_t)n * DIM + dch];
        float r = fmaf(xv, 1.0f + slw[0], acc * weight[dch]);
        out[(size_t)n * DIM + dch] = fminf(fmaxf(r, 0.0f), 1.0f);
    }
}

// ---------------- fallback path (R1): direct float atomics ----------------

__global__ void diffusion_scatter_kernel(const float* __restrict__ x,
                                         const int* __restrict__ src,
                                         const int* __restrict__ dst,
                                         const float* __restrict__ probs,
                                         const float* __restrict__ weight,
                                         float* __restrict__ acc,
                                         int E) {
    int e = blockIdx.x * blockDim.x + threadIdx.x;
    if (e >= E) return;
    int s = src[e];
    int d = dst[e];
    float p = probs[e];
    const float4* xs = reinterpret_cast<const float4*>(x + (size_t)s * DIM);
    const float4* w4 = reinterpret_cast<const float4*>(weight);
    float* outp = acc + (size_t)d * DIM;
#pragma unroll
    for (int q = 0; q < 4; ++q) {
        float4 xv = xs[q];
        float4 wv = w4[q];
        atomicAdd(&outp[q * 4 + 0], xv.x * p * wv.x);
        atomicAdd(&outp[q * 4 + 1], xv.y * p * wv.y);
        atomicAdd(&outp[q * 4 + 2], xv.z * p * wv.z);
        atomicAdd(&outp[q * 4 + 3], xv.w * p * wv.w);
    }
}

__global__ void diffusion_finalize_kernel(const float* __restrict__ x,
                                          const float* __restrict__ slw,
                                          float* __restrict__ out,
                                          int n4) {
    int i = blockIdx.x * blockDim.x + threadIdx.x;
    if (i >= n4) return;
    float s = 1.0f + slw[0];
    float4 xv = reinterpret_cast<const float4*>(x)[i];
    float4 a = reinterpret_cast<float4*>(out)[i];
    float4 r;
    r.x = fminf(fmaxf(fmaf(xv.x, s, a.x), 0.0f), 1.0f);
    r.y = fminf(fmaxf(fmaf(xv.y, s, a.y), 0.0f), 1.0f);
    r.z = fminf(fmaxf(fmaf(xv.z, s, a.z), 0.0f), 1.0f);
    r.w = fminf(fmaxf(fmaf(xv.w, s, a.w), 0.0f), 1.0f);
    reinterpret_cast<float4*>(out)[i] = r;
}

extern "C" void kernel_launch(void* const* d_in, const int* in_sizes, int n_in,
                              void* d_out, int out_size, void* d_ws, size_t ws_size,
                              hipStream_t stream) {
    const float* x      = (const float*)d_in[0];
    const int*   eidx   = (const int*)d_in[1];   // [2, E]: row0=src, row1=dst
    const float* probs  = (const float*)d_in[2];
    const float* weight = (const float*)d_in[3];
    const float* slw    = (const float*)d_in[4];

    int E = in_sizes[2];
    float* out = (float*)d_out;

    // chunk sizing: keep nwg <= TB so the wg-scan fits one block
    int chunk = (E + TB - 1) / TB;
    if (chunk < 8192) chunk = 8192;
    int nwg = (E + chunk - 1) / chunk;

    // ws layout: H[nwg][NB] | totals[NB] | base[NB] | base2[N+1] | (align8)
    //            sorted[E] u64 | sorted2[E] u64
    size_t H_elems = (size_t)nwg * NB;
    size_t head_elems = H_elems + 2 * (size_t)NB + (size_t)N_NODES + 1;
    size_t head = head_elems * sizeof(unsigned);
    head = (head + 7) & ~(size_t)7;
    size_t sorted_bytes = (size_t)E * sizeof(unsigned long long);
    size_t need = head + 2 * sorted_bytes;

    if (ws_size >= need) {
        unsigned* H = (unsigned*)d_ws;
        unsigned* totals = H + H_elems;
        unsigned* basep = totals + NB;
        unsigned* base2 = basep + NB;
        unsigned long long* sorted  = (unsigned long long*)((char*)d_ws + head);
        unsigned long long* sorted2 = (unsigned long long*)((char*)d_ws + head + sorted_bytes);

        hist_kernel<<<nwg, TB, 0, stream>>>(eidx + E, H, E, chunk);
        scan_wg_kernel<<<NB, TB, 0, stream>>>(H, totals, nwg);
        scan_bucket_kernel<<<1, 1024, 0, stream>>>(totals, basep, base2, E);
        place_kernel<<<nwg, TB, 0, stream>>>(eidx, eidx + E, probs, H, basep,
                                             sorted, E, chunk);
        node_sort_kernel<<<NB, 256, 0, stream>>>(basep, totals, sorted, sorted2, base2);
        size_t threads = (size_t)N_NODES * 64;
        gather2_kernel<<<(int)((threads + 255) / 256), 256, 0, stream>>>(
            x, weight, slw, base2, sorted2, out);
    } else {
        const int T = 256;
        hipMemsetAsync(d_out, 0, (size_t)out_size * sizeof(float), stream);
        diffusion_scatter_kernel<<<(E + T - 1) / T, T, 0, stream>>>(
            x, eidx, eidx + E, probs, weight, out, E);
        int n4 = out_size / 4;
        diffusion_finalize_kernel<<<(n4 + T - 1) / T, T, 0, stream>>>(
            x, slw, out, n4);
    }
}

// Round 7
// 123.386 us; speedup vs baseline: 2.9048x; 1.1511x over previous
//
#include <hip/hip_runtime.h>

#define N_NODES 100000
#define DIM 16
#define BSHIFT 7
#define BNODES 128                                  // nodes per bucket
#define NB ((N_NODES + BNODES - 1) / BNODES)        // 782 buckets
#define TB 512
#define CHUNK 8192                                  // edges per place/hist wg
#define CAPB 4608                                   // node_sort LDS capacity (mean 4092 + 8 sigma)

// ---------------- two-level bucket sort + per-node gather ----------------

// A: per-workgroup histogram of dst-buckets (LDS atomics only).
__global__ __launch_bounds__(TB) void hist_kernel(const int* __restrict__ dst,
                                                  unsigned* __restrict__ H,
                                                  int E) {
    __shared__ unsigned hist[NB];
    int tid = threadIdx.x;
    for (int i = tid; i < NB; i += TB) hist[i] = 0;
    __syncthreads();
    int e0 = blockIdx.x * CHUNK;
    int e1 = min(e0 + CHUNK, E);
    for (int e = e0 + tid; e < e1; e += TB)
        atomicAdd(&hist[((unsigned)dst[e]) >> BSHIFT], 1u);
    __syncthreads();
    unsigned* row = H + (size_t)blockIdx.x * NB;
    for (int i = tid; i < NB; i += TB) row[i] = hist[i];
}

// Block-wide exclusive scan (nthreads threads, multiple of 64, <=1024).
__device__ inline unsigned block_scan_excl(unsigned v, int tid, int nthreads,
                                           unsigned* warp_lds, unsigned* total_out) {
    unsigned x = v;
#pragma unroll
    for (int off = 1; off < 64; off <<= 1) {
        unsigned y = __shfl_up(x, off);
        if ((tid & 63) >= off) x += y;
    }
    int wid = tid >> 6;
    int nw = nthreads >> 6;
    if ((tid & 63) == 63) warp_lds[wid] = x;
    __syncthreads();
    if (tid < nw) {
        unsigned w = warp_lds[tid];
#pragma unroll
        for (int off = 1; off < 16; off <<= 1) {
            unsigned y = __shfl_up(w, off);
            if (tid >= off) w += y;
        }
        warp_lds[tid] = w;   // inclusive per-wave totals
    }
    __syncthreads();
    unsigned wbase = (wid > 0) ? warp_lds[wid - 1] : 0u;
    unsigned incl = x + wbase;
    if (total_out && tid == nthreads - 1) *total_out = incl;
    return incl - v;
}

// B1: for each bucket b, exclusive scan of H[wg][b] over wgs (in place) + total.
__global__ __launch_bounds__(TB) void scan_wg_kernel(unsigned* __restrict__ H,
                                                     unsigned* __restrict__ totals,
                                                     int nwg) {
    __shared__ unsigned warp_lds[16];
    int b = blockIdx.x;
    int tid = threadIdx.x;
    unsigned v = (tid < nwg) ? H[(size_t)tid * NB + b] : 0u;
    unsigned excl = block_scan_excl(v, tid, TB, warp_lds, &totals[b]);
    if (tid < nwg) H[(size_t)tid * NB + b] = excl;
}

// B2: exclusive scan of bucket totals -> bucket base offsets; also base2 sentinel.
__global__ __launch_bounds__(1024) void scan_bucket_kernel(const unsigned* __restrict__ totals,
                                                           unsigned* __restrict__ base,
                                                           unsigned* __restrict__ base2,
                                                           int E) {
    __shared__ unsigned warp_lds[16];
    int tid = threadIdx.x;
    unsigned v = (tid < NB) ? totals[tid] : 0u;
    unsigned excl = block_scan_excl(v, tid, 1024, warp_lds, nullptr);
    if (tid < NB) base[tid] = excl;
    if (tid == 0) base2[N_NODES] = (unsigned)E;
}

// C: LDS counting sort of the wg's whole chunk, then wave-cooperative
// coalesced writeout of per-bucket runs (consecutive lanes -> consecutive
// addresses -> ~2 line txns per run instead of one txn per record).
__global__ __launch_bounds__(TB) void place_kernel(const int* __restrict__ src,
                                                   const int* __restrict__ dst,
                                                   const float* __restrict__ probs,
                                                   const unsigned* __restrict__ O,
                                                   const unsigned* __restrict__ base,
                                                   unsigned long long* __restrict__ sorted,
                                                   int E) {
    __shared__ unsigned long long recs[CHUNK];   // 64 KB
    __shared__ unsigned lstart[NB];
    __shared__ unsigned lcur[NB];
    __shared__ unsigned gdst[NB];
    __shared__ unsigned warp_lds[16];
    int tid = threadIdx.x;
    int wg = blockIdx.x;
    int e0 = wg * CHUNK;
    int e1 = min(e0 + CHUNK, E);

    // precompute global run starts for this wg (coalesced loads)
    const unsigned* row = O + (size_t)wg * NB;
    for (int i = tid; i < NB; i += TB) {
        gdst[i] = base[i] + row[i];
        lcur[i] = 0;
    }
    __syncthreads();

    // pass 1: histogram (L3-warm dst re-read)
    for (int e = e0 + tid; e < e1; e += TB)
        atomicAdd(&lcur[((unsigned)dst[e]) >> BSHIFT], 1u);
    __syncthreads();

    // scan 782 bins, 2 per thread
    int b0 = 2 * tid, b1 = 2 * tid + 1;
    unsigned c0 = (b0 < NB) ? lcur[b0] : 0u;
    unsigned c1 = (b1 < NB) ? lcur[b1] : 0u;
    unsigned excl = block_scan_excl(c0 + c1, tid, TB, warp_lds, nullptr);
    __syncthreads();
    if (b0 < NB) { lstart[b0] = excl;      lcur[b0] = excl; }
    if (b1 < NB) { lstart[b1] = excl + c0; lcur[b1] = excl + c0; }
    __syncthreads();

    // pass 2: place records into LDS, bucket-sorted
    for (int e = e0 + tid; e < e1; e += TB) {
        unsigned d = (unsigned)dst[e];
        unsigned s = (unsigned)src[e];
        float p = probs[e];
        unsigned b = d >> BSHIFT;
        unsigned pos = atomicAdd(&lcur[b], 1u);
        recs[pos] = ((unsigned long long)__float_as_uint(p) << 32)
                  | ((d & (BNODES - 1)) << 17) | s;
    }
    __syncthreads();

    // writeout: wave w handles buckets w, w+8, ...
    int wv = tid >> 6, ln = tid & 63;
    for (int b = wv; b < NB; b += (TB >> 6)) {
        unsigned st = lstart[b];
        unsigned cnt = lcur[b] - st;
        unsigned g = gdst[b];
        for (unsigned k = ln; k < cnt; k += 64)
            sorted[g + k] = recs[st + k];
    }
}

// D: one wg per bucket — sort records to node granularity via LDS buffer,
// coalesced read + coalesced write. Falls back to global scatter if the
// bucket exceeds LDS capacity (statistically never).
__global__ __launch_bounds__(TB) void node_sort_kernel(const unsigned* __restrict__ base,
                                                       const unsigned* __restrict__ totals,
                                                       const unsigned long long* __restrict__ sorted,
                                                       unsigned long long* __restrict__ sorted2,
                                                       unsigned* __restrict__ base2) {
    __shared__ unsigned long long buf[CAPB];     // 36.9 KB
    __shared__ unsigned ncnt[BNODES];
    __shared__ unsigned nbase[BNODES];
    int tid = threadIdx.x;
    int b = blockIdx.x;
    unsigned s0 = base[b];
    unsigned cnt = totals[b];

    if (tid < BNODES) ncnt[tid] = 0;
    __syncthreads();
    for (unsigned i = tid; i < cnt; i += TB)
        atomicAdd(&ncnt[((unsigned)sorted[s0 + i] >> 17) & (BNODES - 1)], 1u);
    __syncthreads();
    // exclusive scan of 128 bins by wave 0 (2 bins per lane)
    if (tid < 64) {
        unsigned c0 = ncnt[2 * tid], c1 = ncnt[2 * tid + 1];
        unsigned v = c0 + c1;
        unsigned xs = v;
#pragma unroll
        for (int off = 1; off < 64; off <<= 1) {
            unsigned y = __shfl_up(xs, off);
            if (tid >= off) xs += y;
        }
        nbase[2 * tid]     = xs - v;
        nbase[2 * tid + 1] = xs - c1;
    }
    __syncthreads();
    if (tid < BNODES) {
        int n = b * BNODES + tid;
        if (n < N_NODES) base2[n] = s0 + nbase[tid];
    }
    __syncthreads();

    if (cnt <= CAPB) {
        // place into LDS buffer, then stream out coalesced
        for (unsigned i = tid; i < cnt; i += TB) {
            unsigned long long rec = sorted[s0 + i];     // L3/L2-warm re-read
            unsigned dloc = ((unsigned)rec >> 17) & (BNODES - 1);
            unsigned pos = atomicAdd(&nbase[dloc], 1u);
            buf[pos] = rec;
        }
        __syncthreads();
        for (unsigned i = tid; i < cnt; i += TB)
            sorted2[s0 + i] = buf[i];
    } else {
        // fallback: scatter directly to global (small region, L2-merged)
        for (unsigned i = tid; i < cnt; i += TB) {
            unsigned long long rec = sorted[s0 + i];
            unsigned dloc = ((unsigned)rec >> 17) & (BNODES - 1);
            unsigned pos = atomicAdd(&nbase[dloc], 1u);
            sorted2[s0 + pos] = rec;
        }
    }
}

// E: one wave per node over its contiguous record segment. Register
// accumulation, shfl reduce, fused self-loop + weight + clip.
__global__ __launch_bounds__(256) void gather2_kernel(const float* __restrict__ x,
                                                      const float* __restrict__ weight,
                                                      const float* __restrict__ slw,
                                                      const unsigned* __restrict__ base2,
                                                      const unsigned long long* __restrict__ sorted2,
                                                      float* __restrict__ out) {
    int wave = (int)((blockIdx.x * (size_t)blockDim.x + threadIdx.x) >> 6);
    int lane = threadIdx.x & 63;
    if (wave >= N_NODES) return;
    int n = wave;
    unsigned lo = base2[n];
    unsigned hi = base2[n + 1];
    int sub = lane >> 4;   // record sub-slot 0..3
    int dch = lane & 15;   // dim channel
    float acc = 0.0f;
    unsigned i = lo + (unsigned)sub;
    // 2-deep: 8 records in flight per wave
    for (; i + 4 < hi; i += 8) {
        unsigned long long r0 = sorted2[i];
        unsigned long long r1 = sorted2[i + 4];
        unsigned s0_ = (unsigned)r0 & 0x1FFFFu;
        unsigned s1_ = (unsigned)r1 & 0x1FFFFu;
        float v0 = x[(size_t)s0_ * DIM + dch];
        float v1 = x[(size_t)s1_ * DIM + dch];
        acc = fmaf(v0, __uint_as_float((unsigned)(r0 >> 32)), acc);
        acc = fmaf(v1, __uint_as_float((unsigned)(r1 >> 32)), acc);
    }
    for (; i < hi; i += 4) {
        unsigned long long r0 = sorted2[i];
        unsigned s0_ = (unsigned)r0 & 0x1FFFFu;
        acc = fmaf(x[(size_t)s0_ * DIM + dch],
                   __uint_as_float((unsigned)(r0 >> 32)), acc);
    }
    acc += __shfl_xor(acc, 16);
    acc += __shfl_xor(acc, 32);
    if (lane < 16) {
        float xv = x[(size_t)n * DIM + dch];
        float r = fmaf(xv, 1.0f + slw[0], acc * weight[dch]);
        out[(size_t)n * DIM + dch] = fminf(fmaxf(r, 0.0f), 1.0f);
    }
}

// ---------------- fallback path (R1): direct float atomics ----------------

__global__ void diffusion_scatter_kernel(const float* __restrict__ x,
                                         const int* __restrict__ src,
                                         const int* __restrict__ dst,
                                         const float* __restrict__ probs,
                                         const float* __restrict__ weight,
                                         float* __restrict__ acc,
                                         int E) {
    int e = blockIdx.x * blockDim.x + threadIdx.x;
    if (e >= E) return;
    int s = src[e];
    int d = dst[e];
    float p = probs[e];
    const float4* xs = reinterpret_cast<const float4*>(x + (size_t)s * DIM);
    const float4* w4 = reinterpret_cast<const float4*>(weight);
    float* outp = acc + (size_t)d * DIM;
#pragma unroll
    for (int q = 0; q < 4; ++q) {
        float4 xv = xs[q];
        float4 wv = w4[q];
        atomicAdd(&outp[q * 4 + 0], xv.x * p * wv.x);
        atomicAdd(&outp[q * 4 + 1], xv.y * p * wv.y);
        atomicAdd(&outp[q * 4 + 2], xv.z * p * wv.z);
        atomicAdd(&outp[q * 4 + 3], xv.w * p * wv.w);
    }
}

__global__ void diffusion_finalize_kernel(const float* __restrict__ x,
                                          const float* __restrict__ slw,
                                          float* __restrict__ out,
                                          int n4) {
    int i = blockIdx.x * blockDim.x + threadIdx.x;
    if (i >= n4) return;
    float s = 1.0f + slw[0];
    float4 xv = reinterpret_cast<const float4*>(x)[i];
    float4 a = reinterpret_cast<float4*>(out)[i];
    float4 r;
    r.x = fminf(fmaxf(fmaf(xv.x, s, a.x), 0.0f), 1.0f);
    r.y = fminf(fmaxf(fmaf(xv.y, s, a.y), 0.0f), 1.0f);
    r.z = fminf(fmaxf(fmaf(xv.z, s, a.z), 0.0f), 1.0f);
    r.w = fminf(fmaxf(fmaf(xv.w, s, a.w), 0.0f), 1.0f);
    reinterpret_cast<float4*>(out)[i] = r;
}

extern "C" void kernel_launch(void* const* d_in, const int* in_sizes, int n_in,
                              void* d_out, int out_size, void* d_ws, size_t ws_size,
                              hipStream_t stream) {
    const float* x      = (const float*)d_in[0];
    const int*   eidx   = (const int*)d_in[1];   // [2, E]: row0=src, row1=dst
    const float* probs  = (const float*)d_in[2];
    const float* weight = (const float*)d_in[3];
    const float* slw    = (const float*)d_in[4];

    int E = in_sizes[2];
    float* out = (float*)d_out;

    int nwg = (E + CHUNK - 1) / CHUNK;   // 391 for E=3.2M; wg-scan handles <= TB

    // ws layout: H[nwg][NB] | totals[NB] | base[NB] | base2[N+1] | (align8)
    //            sorted[E] u64 | sorted2[E] u64
    size_t H_elems = (size_t)nwg * NB;
    size_t head_elems = H_elems + 2 * (size_t)NB + (size_t)N_NODES + 1;
    size_t head = head_elems * sizeof(unsigned);
    head = (head + 7) & ~(size_t)7;
    size_t sorted_bytes = (size_t)E * sizeof(unsigned long long);
    size_t need = head + 2 * sorted_bytes;

    if (ws_size >= need && nwg <= TB) {
        unsigned* H = (unsigned*)d_ws;
        unsigned* totals = H + H_elems;
        unsigned* basep = totals + NB;
        unsigned* base2 = basep + NB;
        unsigned long long* sorted  = (unsigned long long*)((char*)d_ws + head);
        unsigned long long* sorted2 = (unsigned long long*)((char*)d_ws + head + sorted_bytes);

        hist_kernel<<<nwg, TB, 0, stream>>>(eidx + E, H, E);
        scan_wg_kernel<<<NB, TB, 0, stream>>>(H, totals, nwg);
        scan_bucket_kernel<<<1, 1024, 0, stream>>>(totals, basep, base2, E);
        place_kernel<<<nwg, TB, 0, stream>>>(eidx, eidx + E, probs, H, basep,
                                             sorted, E);
        node_sort_kernel<<<NB, TB, 0, stream>>>(basep, totals, sorted, sorted2, base2);
        size_t threads = (size_t)N_NODES * 64;
        gather2_kernel<<<(int)((threads + 255) / 256), 256, 0, stream>>>(
            x, weight, slw, base2, sorted2, out);
    } else {
        const int T = 256;
        hipMemsetAsync(d_out, 0, (size_t)out_size * sizeof(float), stream);
        diffusion_scatter_kernel<<<(E + T - 1) / T, T, 0, stream>>>(
            x, eidx, eidx + E, probs, weight, out, E);
        int n4 = out_size / 4;
        diffusion_finalize_kernel<<<(n4 + T - 1) / T, T, 0, stream>>>(
            x, slw, out, n4);
    }
}

// Round 8
// 111.609 us; speedup vs baseline: 3.2113x; 1.1055x over previous
//
#include <hip/hip_runtime.h>
#include <hip/hip_fp16.h>

#define N_NODES 100000
#define DIM 16
#define BSHIFT 7
#define BNODES 128                                  // nodes per bucket
#define NB ((N_NODES + BNODES - 1) / BNODES)        // 782 buckets
#define TB 512
#define CHUNK 8192                                  // edges per place/hist wg
#define CAPB 4608                                   // node_sort LDS capacity

// ---------------- two-level bucket sort + fp16 per-node gather ----------------

// X: convert x (f32) to fp16 once; 8 floats -> 16B per thread.
__global__ __launch_bounds__(256) void convert_x_kernel(const float* __restrict__ x,
                                                        __half* __restrict__ xh,
                                                        int n8) {
    int i = blockIdx.x * 256 + threadIdx.x;
    if (i >= n8) return;
    float4 a = ((const float4*)x)[2 * i];
    float4 b = ((const float4*)x)[2 * i + 1];
    __half2 h0 = __floats2half2_rn(a.x, a.y);
    __half2 h1 = __floats2half2_rn(a.z, a.w);
    __half2 h2 = __floats2half2_rn(b.x, b.y);
    __half2 h3 = __floats2half2_rn(b.z, b.w);
    uint4 u;
    u.x = *reinterpret_cast<unsigned*>(&h0);
    u.y = *reinterpret_cast<unsigned*>(&h1);
    u.z = *reinterpret_cast<unsigned*>(&h2);
    u.w = *reinterpret_cast<unsigned*>(&h3);
    ((uint4*)xh)[i] = u;
}

// A: per-workgroup histogram of dst-buckets (LDS atomics only).
__global__ __launch_bounds__(TB) void hist_kernel(const int* __restrict__ dst,
                                                  unsigned* __restrict__ H,
                                                  int E) {
    __shared__ unsigned hist[NB];
    int tid = threadIdx.x;
    for (int i = tid; i < NB; i += TB) hist[i] = 0;
    __syncthreads();
    int e0 = blockIdx.x * CHUNK;
    int e1 = min(e0 + CHUNK, E);
    for (int e = e0 + tid; e < e1; e += TB)
        atomicAdd(&hist[((unsigned)dst[e]) >> BSHIFT], 1u);
    __syncthreads();
    unsigned* row = H + (size_t)blockIdx.x * NB;
    for (int i = tid; i < NB; i += TB) row[i] = hist[i];
}

// Block-wide exclusive scan (nthreads threads, multiple of 64, <=1024).
__device__ inline unsigned block_scan_excl(unsigned v, int tid, int nthreads,
                                           unsigned* warp_lds, unsigned* total_out) {
    unsigned x = v;
#pragma unroll
    for (int off = 1; off < 64; off <<= 1) {
        unsigned y = __shfl_up(x, off);
        if ((tid & 63) >= off) x += y;
    }
    int wid = tid >> 6;
    int nw = nthreads >> 6;
    if ((tid & 63) == 63) warp_lds[wid] = x;
    __syncthreads();
    if (tid < nw) {
        unsigned w = warp_lds[tid];
#pragma unroll
        for (int off = 1; off < 16; off <<= 1) {
            unsigned y = __shfl_up(w, off);
            if (tid >= off) w += y;
        }
        warp_lds[tid] = w;   // inclusive per-wave totals
    }
    __syncthreads();
    unsigned wbase = (wid > 0) ? warp_lds[wid - 1] : 0u;
    unsigned incl = x + wbase;
    if (total_out && tid == nthreads - 1) *total_out = incl;
    return incl - v;
}

// B1: for each bucket b, exclusive scan of H[wg][b] over wgs (in place) + total.
__global__ __launch_bounds__(TB) void scan_wg_kernel(unsigned* __restrict__ H,
                                                     unsigned* __restrict__ totals,
                                                     int nwg) {
    __shared__ unsigned warp_lds[16];
    int b = blockIdx.x;
    int tid = threadIdx.x;
    unsigned v = (tid < nwg) ? H[(size_t)tid * NB + b] : 0u;
    unsigned excl = block_scan_excl(v, tid, TB, warp_lds, &totals[b]);
    if (tid < nwg) H[(size_t)tid * NB + b] = excl;
}

// B2: exclusive scan of bucket totals -> bucket base offsets; also base2 sentinel.
__global__ __launch_bounds__(1024) void scan_bucket_kernel(const unsigned* __restrict__ totals,
                                                           unsigned* __restrict__ base,
                                                           unsigned* __restrict__ base2,
                                                           int E) {
    __shared__ unsigned warp_lds[16];
    int tid = threadIdx.x;
    unsigned v = (tid < NB) ? totals[tid] : 0u;
    unsigned excl = block_scan_excl(v, tid, 1024, warp_lds, nullptr);
    if (tid < NB) base[tid] = excl;
    if (tid == 0) base2[N_NODES] = (unsigned)E;
}

// C: LDS counting sort of the wg's chunk into compact (u32 idx, fp16 p)
// records, then wave-cooperative coalesced writeout of per-bucket runs.
__global__ __launch_bounds__(TB) void place_kernel(const int* __restrict__ src,
                                                   const int* __restrict__ dst,
                                                   const float* __restrict__ probs,
                                                   const unsigned* __restrict__ O,
                                                   const unsigned* __restrict__ base,
                                                   unsigned* __restrict__ sorted_idx,
                                                   __half* __restrict__ sorted_p,
                                                   int E) {
    __shared__ unsigned recs_idx[CHUNK];         // 32 KB
    __shared__ __half  recs_p[CHUNK];            // 16 KB
    __shared__ unsigned lstart[NB];
    __shared__ unsigned lcur[NB];
    __shared__ unsigned gdst[NB];
    __shared__ unsigned warp_lds[16];
    int tid = threadIdx.x;
    int wg = blockIdx.x;
    int e0 = wg * CHUNK;
    int e1 = min(e0 + CHUNK, E);

    const unsigned* row = O + (size_t)wg * NB;
    for (int i = tid; i < NB; i += TB) {
        gdst[i] = base[i] + row[i];
        lcur[i] = 0;
    }
    __syncthreads();

    // pass 1: histogram (L3-warm dst re-read)
    for (int e = e0 + tid; e < e1; e += TB)
        atomicAdd(&lcur[((unsigned)dst[e]) >> BSHIFT], 1u);
    __syncthreads();

    // scan 782 bins, 2 per thread
    int b0 = 2 * tid, b1 = 2 * tid + 1;
    unsigned c0 = (b0 < NB) ? lcur[b0] : 0u;
    unsigned c1 = (b1 < NB) ? lcur[b1] : 0u;
    unsigned excl = block_scan_excl(c0 + c1, tid, TB, warp_lds, nullptr);
    __syncthreads();
    if (b0 < NB) { lstart[b0] = excl;      lcur[b0] = excl; }
    if (b1 < NB) { lstart[b1] = excl + c0; lcur[b1] = excl + c0; }
    __syncthreads();

    // pass 2: place records into LDS, bucket-sorted
    for (int e = e0 + tid; e < e1; e += TB) {
        unsigned d = (unsigned)dst[e];
        unsigned s = (unsigned)src[e];
        float p = probs[e];
        unsigned b = d >> BSHIFT;
        unsigned pos = atomicAdd(&lcur[b], 1u);
        recs_idx[pos] = ((d & (BNODES - 1)) << 17) | s;   // dloc 7b | src 17b
        recs_p[pos] = __float2half_rn(p);
    }
    __syncthreads();

    // writeout: wave w handles buckets w, w+8, ... (coalesced runs)
    int wv = tid >> 6, ln = tid & 63;
    for (int b = wv; b < NB; b += (TB >> 6)) {
        unsigned st = lstart[b];
        unsigned cnt = lcur[b] - st;
        unsigned g = gdst[b];
        for (unsigned k = ln; k < cnt; k += 64) {
            sorted_idx[g + k] = recs_idx[st + k];
            sorted_p[g + k] = recs_p[st + k];
        }
    }
}

// D: one wg per bucket — sort records to node granularity via LDS buffers,
// coalesced read + coalesced write; global-scatter fallback on overflow.
__global__ __launch_bounds__(TB) void node_sort_kernel(const unsigned* __restrict__ base,
                                                       const unsigned* __restrict__ totals,
                                                       const unsigned* __restrict__ sorted_idx,
                                                       const __half* __restrict__ sorted_p,
                                                       unsigned* __restrict__ sorted2_idx,
                                                       __half* __restrict__ sorted2_p,
                                                       unsigned* __restrict__ base2) {
    __shared__ unsigned buf_idx[CAPB];           // 18.4 KB
    __shared__ __half  buf_p[CAPB];              // 9.2 KB
    __shared__ unsigned ncnt[BNODES];
    __shared__ unsigned nbase[BNODES];
    int tid = threadIdx.x;
    int b = blockIdx.x;
    unsigned s0 = base[b];
    unsigned cnt = totals[b];

    if (tid < BNODES) ncnt[tid] = 0;
    __syncthreads();
    for (unsigned i = tid; i < cnt; i += TB)
        atomicAdd(&ncnt[(sorted_idx[s0 + i] >> 17) & (BNODES - 1)], 1u);
    __syncthreads();
    if (tid < 64) {
        unsigned c0 = ncnt[2 * tid], c1 = ncnt[2 * tid + 1];
        unsigned v = c0 + c1;
        unsigned xs = v;
#pragma unroll
        for (int off = 1; off < 64; off <<= 1) {
            unsigned y = __shfl_up(xs, off);
            if (tid >= off) xs += y;
        }
        nbase[2 * tid]     = xs - v;
        nbase[2 * tid + 1] = xs - c1;
    }
    __syncthreads();
    if (tid < BNODES) {
        int n = b * BNODES + tid;
        if (n < N_NODES) base2[n] = s0 + nbase[tid];
    }
    __syncthreads();

    if (cnt <= CAPB) {
        for (unsigned i = tid; i < cnt; i += TB) {
            unsigned v = sorted_idx[s0 + i];
            __half p = sorted_p[s0 + i];
            unsigned pos = atomicAdd(&nbase[(v >> 17) & (BNODES - 1)], 1u);
            buf_idx[pos] = v;
            buf_p[pos] = p;
        }
        __syncthreads();
        for (unsigned i = tid; i < cnt; i += TB) {
            sorted2_idx[s0 + i] = buf_idx[i];
            sorted2_p[s0 + i] = buf_p[i];
        }
    } else {
        for (unsigned i = tid; i < cnt; i += TB) {
            unsigned v = sorted_idx[s0 + i];
            __half p = sorted_p[s0 + i];
            unsigned pos = atomicAdd(&nbase[(v >> 17) & (BNODES - 1)], 1u);
            sorted2_idx[s0 + pos] = v;
            sorted2_p[s0 + pos] = p;
        }
    }
}

// E: one wave per node; 8 lanes per edge (half2 per lane), 8 edges in flight.
// fp16 x-gather (L2-resident), f32 accumulate, shfl reduce, fused epilogue.
__global__ __launch_bounds__(256) void gather2_kernel(const float* __restrict__ x,
                                                      const __half* __restrict__ xh,
                                                      const float* __restrict__ weight,
                                                      const float* __restrict__ slw,
                                                      const unsigned* __restrict__ base2,
                                                      const unsigned* __restrict__ sorted2_idx,
                                                      const __half* __restrict__ sorted2_p,
                                                      float* __restrict__ out) {
    int wave = (int)((blockIdx.x * (size_t)blockDim.x + threadIdx.x) >> 6);
    int lane = threadIdx.x & 63;
    if (wave >= N_NODES) return;
    int n = wave;
    unsigned lo = base2[n];
    unsigned hi = base2[n + 1];
    int sub = lane >> 3;   // edge sub-slot 0..7
    int dc  = lane & 7;    // half2 channel (dims 2dc, 2dc+1)
    float ax = 0.0f, ay = 0.0f;
    const __half2* xh2 = (const __half2*)xh;
    unsigned i = lo + (unsigned)sub;
    for (; i + 8 < hi; i += 16) {      // 16 records in flight per wave
        unsigned v0 = sorted2_idx[i];
        unsigned v1 = sorted2_idx[i + 8];
        float p0 = __half2float(sorted2_p[i]);
        float p1 = __half2float(sorted2_p[i + 8]);
        float2 f0 = __half22float2(xh2[(size_t)(v0 & 0x1FFFFu) * 8 + dc]);
        float2 f1 = __half22float2(xh2[(size_t)(v1 & 0x1FFFFu) * 8 + dc]);
        ax = fmaf(f0.x, p0, ax); ay = fmaf(f0.y, p0, ay);
        ax = fmaf(f1.x, p1, ax); ay = fmaf(f1.y, p1, ay);
    }
    for (; i < hi; i += 8) {
        unsigned v0 = sorted2_idx[i];
        float p0 = __half2float(sorted2_p[i]);
        float2 f0 = __half22float2(xh2[(size_t)(v0 & 0x1FFFFu) * 8 + dc]);
        ax = fmaf(f0.x, p0, ax); ay = fmaf(f0.y, p0, ay);
    }
    ax += __shfl_xor(ax, 8);  ay += __shfl_xor(ay, 8);
    ax += __shfl_xor(ax, 16); ay += __shfl_xor(ay, 16);
    ax += __shfl_xor(ax, 32); ay += __shfl_xor(ay, 32);
    if (lane < 8) {
        float sc = 1.0f + slw[0];
        float2 xv = ((const float2*)x)[(size_t)n * 8 + dc];
        float2 wv = ((const float2*)weight)[dc];
        float2 r;
        r.x = fminf(fmaxf(fmaf(xv.x, sc, ax * wv.x), 0.0f), 1.0f);
        r.y = fminf(fmaxf(fmaf(xv.y, sc, ay * wv.y), 0.0f), 1.0f);
        ((float2*)out)[(size_t)n * 8 + dc] = r;
    }
}

// ---------------- fallback path (R1): direct float atomics ----------------

__global__ void diffusion_scatter_kernel(const float* __restrict__ x,
                                         const int* __restrict__ src,
                                         const int* __restrict__ dst,
                                         const float* __restrict__ probs,
                                         const float* __restrict__ weight,
                                         float* __restrict__ acc,
                                         int E) {
    int e = blockIdx.x * blockDim.x + threadIdx.x;
    if (e >= E) return;
    int s = src[e];
    int d = dst[e];
    float p = probs[e];
    const float4* xs = reinterpret_cast<const float4*>(x + (size_t)s * DIM);
    const float4* w4 = reinterpret_cast<const float4*>(weight);
    float* outp = acc + (size_t)d * DIM;
#pragma unroll
    for (int q = 0; q < 4; ++q) {
        float4 xv = xs[q];
        float4 wv = w4[q];
        atomicAdd(&outp[q * 4 + 0], xv.x * p * wv.x);
        atomicAdd(&outp[q * 4 + 1], xv.y * p * wv.y);
        atomicAdd(&outp[q * 4 + 2], xv.z * p * wv.z);
        atomicAdd(&outp[q * 4 + 3], xv.w * p * wv.w);
    }
}

__global__ void diffusion_finalize_kernel(const float* __restrict__ x,
                                          const float* __restrict__ slw,
                                          float* __restrict__ out,
                                          int n4) {
    int i = blockIdx.x * blockDim.x + threadIdx.x;
    if (i >= n4) return;
    float s = 1.0f + slw[0];
    float4 xv = reinterpret_cast<const float4*>(x)[i];
    float4 a = reinterpret_cast<float4*>(out)[i];
    float4 r;
    r.x = fminf(fmaxf(fmaf(xv.x, s, a.x), 0.0f), 1.0f);
    r.y = fminf(fmaxf(fmaf(xv.y, s, a.y), 0.0f), 1.0f);
    r.z = fminf(fmaxf(fmaf(xv.z, s, a.z), 0.0f), 1.0f);
    r.w = fminf(fmaxf(fmaf(xv.w, s, a.w), 0.0f), 1.0f);
    reinterpret_cast<float4*>(out)[i] = r;
}

extern "C" void kernel_launch(void* const* d_in, const int* in_sizes, int n_in,
                              void* d_out, int out_size, void* d_ws, size_t ws_size,
                              hipStream_t stream) {
    const float* x      = (const float*)d_in[0];
    const int*   eidx   = (const int*)d_in[1];   // [2, E]: row0=src, row1=dst
    const float* probs  = (const float*)d_in[2];
    const float* weight = (const float*)d_in[3];
    const float* slw    = (const float*)d_in[4];

    int E = in_sizes[2];
    float* out = (float*)d_out;

    int nwg = (E + CHUNK - 1) / CHUNK;   // 391 for E=3.2M

    // ws layout (16B-aligned segments):
    // H[nwg*NB] u32 | totals[NB] | base[NB] | base2[N+1] |
    // xh[N*DIM] fp16 | sorted_idx[E] u32 | sorted2_idx[E] u32 |
    // sorted_p[E] fp16 | sorted2_p[E] fp16
    size_t off = 0;
    auto alloc = [&](size_t bytes) { size_t o = off; off += (bytes + 15) & ~(size_t)15; return o; };
    size_t o_H       = alloc((size_t)nwg * NB * 4);
    size_t o_totals  = alloc((size_t)NB * 4);
    size_t o_base    = alloc((size_t)NB * 4);
    size_t o_base2   = alloc(((size_t)N_NODES + 1) * 4);
    size_t o_xh      = alloc((size_t)N_NODES * DIM * 2);
    size_t o_sidx    = alloc((size_t)E * 4);
    size_t o_s2idx   = alloc((size_t)E * 4);
    size_t o_sp      = alloc((size_t)E * 2);
    size_t o_s2p     = alloc((size_t)E * 2);
    size_t need = off;

    if (ws_size >= need && nwg <= TB) {
        char* ws = (char*)d_ws;
        unsigned* H           = (unsigned*)(ws + o_H);
        unsigned* totals      = (unsigned*)(ws + o_totals);
        unsigned* basep       = (unsigned*)(ws + o_base);
        unsigned* base2       = (unsigned*)(ws + o_base2);
        __half*   xh          = (__half*)(ws + o_xh);
        unsigned* sorted_idx  = (unsigned*)(ws + o_sidx);
        unsigned* sorted2_idx = (unsigned*)(ws + o_s2idx);
        __half*   sorted_p    = (__half*)(ws + o_sp);
        __half*   sorted2_p   = (__half*)(ws + o_s2p);

        int n8 = N_NODES * DIM / 8;
        convert_x_kernel<<<(n8 + 255) / 256, 256, 0, stream>>>(x, xh, n8);
        hist_kernel<<<nwg, TB, 0, stream>>>(eidx + E, H, E);
        scan_wg_kernel<<<NB, TB, 0, stream>>>(H, totals, nwg);
        scan_bucket_kernel<<<1, 1024, 0, stream>>>(totals, basep, base2, E);
        place_kernel<<<nwg, TB, 0, stream>>>(eidx, eidx + E, probs, H, basep,
                                             sorted_idx, sorted_p, E);
        node_sort_kernel<<<NB, TB, 0, stream>>>(basep, totals, sorted_idx, sorted_p,
                                                sorted2_idx, sorted2_p, base2);
        size_t threads = (size_t)N_NODES * 64;
        gather2_kernel<<<(int)((threads + 255) / 256), 256, 0, stream>>>(
            x, xh, weight, slw, base2, sorted2_idx, sorted2_p, out);
    } else {
        const int T = 256;
        hipMemsetAsync(d_out, 0, (size_t)out_size * sizeof(float), stream);
        diffusion_scatter_kernel<<<(E + T - 1) / T, T, 0, stream>>>(
            x, eidx, eidx + E, probs, weight, out, E);
        int n4 = out_size / 4;
        diffusion_finalize_kernel<<<(n4 + T - 1) / T, T, 0, stream>>>(
            x, slw, out, n4);
    }
}

// Round 9
// 92.690 us; speedup vs baseline: 3.8667x; 1.2041x over previous
//
#include <hip/hip_runtime.h>
#include <hip/hip_fp16.h>

#define N_NODES 100000
#define DIM 16
#define BSHIFT 7
#define BNODES 128                                  // nodes per bucket
#define NB ((N_NODES + BNODES - 1) / BNODES)        // 782 buckets
#define TB 512
#define CHUNK 8192                                  // edges per place/hist wg
#define CAPB 4608                                   // node_sort LDS capacity
#define QSCALE 32767.0f

// ---------------- two-level bucket sort + fp16 per-node gather ----------------

// X: convert x (f32) to fp16 once; 8 floats -> 16B per thread.
__global__ __launch_bounds__(256) void convert_x_kernel(const float* __restrict__ x,
                                                        __half* __restrict__ xh,
                                                        int n8) {
    int i = blockIdx.x * 256 + threadIdx.x;
    if (i >= n8) return;
    float4 a = ((const float4*)x)[2 * i];
    float4 b = ((const float4*)x)[2 * i + 1];
    __half2 h0 = __floats2half2_rn(a.x, a.y);
    __half2 h1 = __floats2half2_rn(a.z, a.w);
    __half2 h2 = __floats2half2_rn(b.x, b.y);
    __half2 h3 = __floats2half2_rn(b.z, b.w);
    uint4 u;
    u.x = *reinterpret_cast<unsigned*>(&h0);
    u.y = *reinterpret_cast<unsigned*>(&h1);
    u.z = *reinterpret_cast<unsigned*>(&h2);
    u.w = *reinterpret_cast<unsigned*>(&h3);
    ((uint4*)xh)[i] = u;
}

// A: per-workgroup histogram of dst-buckets (LDS atomics only).
__global__ __launch_bounds__(TB) void hist_kernel(const int* __restrict__ dst,
                                                  unsigned* __restrict__ H,
                                                  int E) {
    __shared__ unsigned hist[NB];
    int tid = threadIdx.x;
    for (int i = tid; i < NB; i += TB) hist[i] = 0;
    __syncthreads();
    int e0 = blockIdx.x * CHUNK;
    int e1 = min(e0 + CHUNK, E);
    for (int e = e0 + tid; e < e1; e += TB)
        atomicAdd(&hist[((unsigned)dst[e]) >> BSHIFT], 1u);
    __syncthreads();
    unsigned* row = H + (size_t)blockIdx.x * NB;
    for (int i = tid; i < NB; i += TB) row[i] = hist[i];
}

// Block-wide exclusive scan (nthreads threads, multiple of 64, <=1024).
__device__ inline unsigned block_scan_excl(unsigned v, int tid, int nthreads,
                                           unsigned* warp_lds, unsigned* total_out) {
    unsigned x = v;
#pragma unroll
    for (int off = 1; off < 64; off <<= 1) {
        unsigned y = __shfl_up(x, off);
        if ((tid & 63) >= off) x += y;
    }
    int wid = tid >> 6;
    int nw = nthreads >> 6;
    if ((tid & 63) == 63) warp_lds[wid] = x;
    __syncthreads();
    if (tid < nw) {
        unsigned w = warp_lds[tid];
#pragma unroll
        for (int off = 1; off < 16; off <<= 1) {
            unsigned y = __shfl_up(w, off);
            if (tid >= off) w += y;
        }
        warp_lds[tid] = w;   // inclusive per-wave totals
    }
    __syncthreads();
    unsigned wbase = (wid > 0) ? warp_lds[wid - 1] : 0u;
    unsigned incl = x + wbase;
    if (total_out && tid == nthreads - 1) *total_out = incl;
    return incl - v;
}

// B1: for each bucket b, exclusive scan of H[wg][b] over wgs (in place) + total.
__global__ __launch_bounds__(TB) void scan_wg_kernel(unsigned* __restrict__ H,
                                                     unsigned* __restrict__ totals,
                                                     int nwg) {
    __shared__ unsigned warp_lds[16];
    int b = blockIdx.x;
    int tid = threadIdx.x;
    unsigned v = (tid < nwg) ? H[(size_t)tid * NB + b] : 0u;
    unsigned excl = block_scan_excl(v, tid, TB, warp_lds, &totals[b]);
    if (tid < nwg) H[(size_t)tid * NB + b] = excl;
}

// B2: exclusive scan of bucket totals -> bucket base offsets; also base2 sentinel.
__global__ __launch_bounds__(1024) void scan_bucket_kernel(const unsigned* __restrict__ totals,
                                                           unsigned* __restrict__ base,
                                                           unsigned* __restrict__ base2,
                                                           int E) {
    __shared__ unsigned warp_lds[16];
    int tid = threadIdx.x;
    unsigned v = (tid < NB) ? totals[tid] : 0u;
    unsigned excl = block_scan_excl(v, tid, 1024, warp_lds, nullptr);
    if (tid < NB) base[tid] = excl;
    if (tid == 0) base2[N_NODES] = (unsigned)E;
}

// C: LDS counting sort of the wg's chunk into (u32 dloc|src, u16 p-fixed15)
// records. Chunk counts derived by diffing adjacent scanned H rows (no
// histogram pass). Writeout: 16 lanes per bucket, 4 buckets per wave.
__global__ __launch_bounds__(TB) void place_kernel(const int* __restrict__ src,
                                                   const int* __restrict__ dst,
                                                   const float* __restrict__ probs,
                                                   const unsigned* __restrict__ O,
                                                   const unsigned* __restrict__ totals,
                                                   const unsigned* __restrict__ base,
                                                   unsigned* __restrict__ sorted_idx,
                                                   unsigned short* __restrict__ sorted_q,
                                                   int E, int nwg) {
    __shared__ unsigned recs_idx[CHUNK];          // 32 KB
    __shared__ unsigned short recs_q[CHUNK];      // 16 KB
    __shared__ unsigned lstart[NB];
    __shared__ unsigned lcur[NB];
    __shared__ unsigned gdst[NB];
    __shared__ unsigned warp_lds[16];
    int tid = threadIdx.x;
    int wg = blockIdx.x;
    int e0 = wg * CHUNK;
    int e1 = min(e0 + CHUNK, E);
    bool last = (wg == nwg - 1);

    // per-chunk counts = H[wg+1] - H[wg] (last: totals - H[wg]); gdst = base + H[wg]
    const unsigned* row  = O + (size_t)wg * NB;
    const unsigned* rown = O + (size_t)(wg + 1) * NB;
    for (int i = tid; i < NB; i += TB) {
        unsigned h = row[i];
        unsigned hn = last ? totals[i] : rown[i];
        gdst[i] = base[i] + h;
        lcur[i] = hn - h;                  // count for this wg
    }
    __syncthreads();

    // scan 782 bins, 2 per thread
    int b0 = 2 * tid, b1 = 2 * tid + 1;
    unsigned c0 = (b0 < NB) ? lcur[b0] : 0u;
    unsigned c1 = (b1 < NB) ? lcur[b1] : 0u;
    unsigned excl = block_scan_excl(c0 + c1, tid, TB, warp_lds, nullptr);
    __syncthreads();
    if (b0 < NB) { lstart[b0] = excl;      lcur[b0] = excl; }
    if (b1 < NB) { lstart[b1] = excl + c0; lcur[b1] = excl + c0; }
    __syncthreads();

    // place records into LDS, bucket-sorted
    for (int e = e0 + tid; e < e1; e += TB) {
        unsigned d = (unsigned)dst[e];
        unsigned s = (unsigned)src[e];
        float p = probs[e];
        unsigned b = d >> BSHIFT;
        unsigned pos = atomicAdd(&lcur[b], 1u);
        recs_idx[pos] = ((d & (BNODES - 1)) << 17) | s;   // dloc 7b | src 17b
        recs_q[pos] = (unsigned short)__float2uint_rn(p * QSCALE);
    }
    __syncthreads();

    // writeout: 16 lanes per bucket, 4 buckets per wave (runs avg ~10 recs)
    int wv = tid >> 6, ln = tid & 63;
    int bq = ln >> 4, ln16 = ln & 15;
    for (int bb = wv * 4; bb < NB; bb += (TB >> 6) * 4) {
        int b = bb + bq;
        unsigned st = 0, cnt = 0, g = 0;
        if (b < NB) { st = lstart[b]; cnt = lcur[b] - st; g = gdst[b]; }
        for (unsigned k = ln16; k < cnt; k += 16) {
            sorted_idx[g + k] = recs_idx[st + k];
            sorted_q[g + k]   = recs_q[st + k];
        }
    }
}

// D: one wg per bucket — node-granularity sort via LDS; emits packed
// u32 records (src<<15 | q15). Global-scatter fallback on overflow.
__global__ __launch_bounds__(TB) void node_sort_kernel(const unsigned* __restrict__ base,
                                                       const unsigned* __restrict__ totals,
                                                       const unsigned* __restrict__ sorted_idx,
                                                       const unsigned short* __restrict__ sorted_q,
                                                       unsigned* __restrict__ sorted2,
                                                       unsigned* __restrict__ base2) {
    __shared__ unsigned buf[CAPB];                // 18.4 KB
    __shared__ unsigned ncnt[BNODES];
    __shared__ unsigned nbase[BNODES];
    int tid = threadIdx.x;
    int b = blockIdx.x;
    unsigned s0 = base[b];
    unsigned cnt = totals[b];

    if (tid < BNODES) ncnt[tid] = 0;
    __syncthreads();
    for (unsigned i = tid; i < cnt; i += TB)
        atomicAdd(&ncnt[(sorted_idx[s0 + i] >> 17) & (BNODES - 1)], 1u);
    __syncthreads();
    if (tid < 64) {
        unsigned c0 = ncnt[2 * tid], c1 = ncnt[2 * tid + 1];
        unsigned v = c0 + c1;
        unsigned xs = v;
#pragma unroll
        for (int off = 1; off < 64; off <<= 1) {
            unsigned y = __shfl_up(xs, off);
            if (tid >= off) xs += y;
        }
        nbase[2 * tid]     = xs - v;
        nbase[2 * tid + 1] = xs - c1;
    }
    __syncthreads();
    if (tid < BNODES) {
        int n = b * BNODES + tid;
        if (n < N_NODES) base2[n] = s0 + nbase[tid];
    }
    __syncthreads();

    if (cnt <= CAPB) {
        for (unsigned i = tid; i < cnt; i += TB) {
            unsigned v = sorted_idx[s0 + i];
            unsigned q = sorted_q[s0 + i];
            unsigned pos = atomicAdd(&nbase[(v >> 17) & (BNODES - 1)], 1u);
            buf[pos] = ((v & 0x1FFFFu) << 15) | q;
        }
        __syncthreads();
        for (unsigned i = tid; i < cnt; i += TB)
            sorted2[s0 + i] = buf[i];
    } else {
        for (unsigned i = tid; i < cnt; i += TB) {
            unsigned v = sorted_idx[s0 + i];
            unsigned q = sorted_q[s0 + i];
            unsigned pos = atomicAdd(&nbase[(v >> 17) & (BNODES - 1)], 1u);
            sorted2[s0 + pos] = ((v & 0x1FFFFu) << 15) | q;
        }
    }
}

// E: one wave per node; 8 lanes per edge (half2 per lane), 4-deep pipeline
// (32 records per pass, 8 loads in flight). Packed u32 records; exec-masked
// guards (r=0 -> p=0 contributes nothing). fp16 x-gather, f32 accumulate.
__global__ __launch_bounds__(256) void gather2_kernel(const float* __restrict__ x,
                                                      const __half* __restrict__ xh,
                                                      const float* __restrict__ weight,
                                                      const float* __restrict__ slw,
                                                      const unsigned* __restrict__ base2,
                                                      const unsigned* __restrict__ sorted2,
                                                      float* __restrict__ out) {
    int wave = (int)((blockIdx.x * (size_t)blockDim.x + threadIdx.x) >> 6);
    int lane = threadIdx.x & 63;
    if (wave >= N_NODES) return;
    int n = wave;
    unsigned lo = base2[n];
    unsigned hi = base2[n + 1];
    int sub = lane >> 3;   // record sub-slot 0..7
    int dc  = lane & 7;    // half2 channel (dims 2dc, 2dc+1)
    const __half2* xh2 = (const __half2*)xh;
    const float QS = 1.0f / QSCALE;
    float ax = 0.0f, ay = 0.0f;
    for (unsigned i = lo + (unsigned)sub; i < hi; i += 32) {
        unsigned i1 = i + 8, i2 = i + 16, i3 = i + 24;
        unsigned r0 = sorted2[i];
        unsigned r1 = (i1 < hi) ? sorted2[i1] : 0u;
        unsigned r2 = (i2 < hi) ? sorted2[i2] : 0u;
        unsigned r3 = (i3 < hi) ? sorted2[i3] : 0u;
        float2 f0 = __half22float2(xh2[(size_t)(r0 >> 15) * 8 + dc]);
        float2 f1 = __half22float2(xh2[(size_t)(r1 >> 15) * 8 + dc]);
        float2 f2 = __half22float2(xh2[(size_t)(r2 >> 15) * 8 + dc]);
        float2 f3 = __half22float2(xh2[(size_t)(r3 >> 15) * 8 + dc]);
        float p0 = (float)(r0 & 0x7FFFu) * QS;
        float p1 = (float)(r1 & 0x7FFFu) * QS;
        float p2 = (float)(r2 & 0x7FFFu) * QS;
        float p3 = (float)(r3 & 0x7FFFu) * QS;
        ax = fmaf(f0.x, p0, ax); ay = fmaf(f0.y, p0, ay);
        ax = fmaf(f1.x, p1, ax); ay = fmaf(f1.y, p1, ay);
        ax = fmaf(f2.x, p2, ax); ay = fmaf(f2.y, p2, ay);
        ax = fmaf(f3.x, p3, ax); ay = fmaf(f3.y, p3, ay);
    }
    ax += __shfl_xor(ax, 8);  ay += __shfl_xor(ay, 8);
    ax += __shfl_xor(ax, 16); ay += __shfl_xor(ay, 16);
    ax += __shfl_xor(ax, 32); ay += __shfl_xor(ay, 32);
    if (lane < 8) {
        float sc = 1.0f + slw[0];
        float2 xv = ((const float2*)x)[(size_t)n * 8 + dc];
        float2 wv = ((const float2*)weight)[dc];
        float2 r;
        r.x = fminf(fmaxf(fmaf(xv.x, sc, ax * wv.x), 0.0f), 1.0f);
        r.y = fminf(fmaxf(fmaf(xv.y, sc, ay * wv.y), 0.0f), 1.0f);
        ((float2*)out)[(size_t)n * 8 + dc] = r;
    }
}

// ---------------- fallback path (R1): direct float atomics ----------------

__global__ void diffusion_scatter_kernel(const float* __restrict__ x,
                                         const int* __restrict__ src,
                                         const int* __restrict__ dst,
                                         const float* __restrict__ probs,
                                         const float* __restrict__ weight,
                                         float* __restrict__ acc,
                                         int E) {
    int e = blockIdx.x * blockDim.x + threadIdx.x;
    if (e >= E) return;
    int s = src[e];
    int d = dst[e];
    float p = probs[e];
    const float4* xs = reinterpret_cast<const float4*>(x + (size_t)s * DIM);
    const float4* w4 = reinterpret_cast<const float4*>(weight);
    float* outp = acc + (size_t)d * DIM;
#pragma unroll
    for (int q = 0; q < 4; ++q) {
        float4 xv = xs[q];
        float4 wv = w4[q];
        atomicAdd(&outp[q * 4 + 0], xv.x * p * wv.x);
        atomicAdd(&outp[q * 4 + 1], xv.y * p * wv.y);
        atomicAdd(&outp[q * 4 + 2], xv.z * p * wv.z);
        atomicAdd(&outp[q * 4 + 3], xv.w * p * wv.w);
    }
}

__global__ void diffusion_finalize_kernel(const float* __restrict__ x,
                                          const float* __restrict__ slw,
                                          float* __restrict__ out,
                                          int n4) {
    int i = blockIdx.x * blockDim.x + threadIdx.x;
    if (i >= n4) return;
    float s = 1.0f + slw[0];
    float4 xv = reinterpret_cast<const float4*>(x)[i];
    float4 a = reinterpret_cast<float4*>(out)[i];
    float4 r;
    r.x = fminf(fmaxf(fmaf(xv.x, s, a.x), 0.0f), 1.0f);
    r.y = fminf(fmaxf(fmaf(xv.y, s, a.y), 0.0f), 1.0f);
    r.z = fminf(fmaxf(fmaf(xv.z, s, a.z), 0.0f), 1.0f);
    r.w = fminf(fmaxf(fmaf(xv.w, s, a.w), 0.0f), 1.0f);
    reinterpret_cast<float4*>(out)[i] = r;
}

extern "C" void kernel_launch(void* const* d_in, const int* in_sizes, int n_in,
                              void* d_out, int out_size, void* d_ws, size_t ws_size,
                              hipStream_t stream) {
    const float* x      = (const float*)d_in[0];
    const int*   eidx   = (const int*)d_in[1];   // [2, E]: row0=src, row1=dst
    const float* probs  = (const float*)d_in[2];
    const float* weight = (const float*)d_in[3];
    const float* slw    = (const float*)d_in[4];

    int E = in_sizes[2];
    float* out = (float*)d_out;

    int nwg = (E + CHUNK - 1) / CHUNK;   // 391 for E=3.2M

    // ws layout (16B-aligned segments):
    // H[nwg*NB] u32 | totals[NB] | base[NB] | base2[N+1] |
    // xh[N*DIM] fp16 | sorted_idx[E] u32 | sorted_q[E] u16 | sorted2[E] u32
    size_t off = 0;
    auto alloc = [&](size_t bytes) { size_t o = off; off += (bytes + 15) & ~(size_t)15; return o; };
    size_t o_H       = alloc((size_t)nwg * NB * 4);
    size_t o_totals  = alloc((size_t)NB * 4);
    size_t o_base    = alloc((size_t)NB * 4);
    size_t o_base2   = alloc(((size_t)N_NODES + 1) * 4);
    size_t o_xh      = alloc((size_t)N_NODES * DIM * 2);
    size_t o_sidx    = alloc((size_t)E * 4);
    size_t o_sq      = alloc((size_t)E * 2);
    size_t o_s2      = alloc((size_t)E * 4);
    size_t need = off;

    if (ws_size >= need && nwg <= TB) {
        char* ws = (char*)d_ws;
        unsigned* H           = (unsigned*)(ws + o_H);
        unsigned* totals      = (unsigned*)(ws + o_totals);
        unsigned* basep       = (unsigned*)(ws + o_base);
        unsigned* base2       = (unsigned*)(ws + o_base2);
        __half*   xh          = (__half*)(ws + o_xh);
        unsigned* sorted_idx  = (unsigned*)(ws + o_sidx);
        unsigned short* sorted_q = (unsigned short*)(ws + o_sq);
        unsigned* sorted2     = (unsigned*)(ws + o_s2);

        int n8 = N_NODES * DIM / 8;
        convert_x_kernel<<<(n8 + 255) / 256, 256, 0, stream>>>(x, xh, n8);
        hist_kernel<<<nwg, TB, 0, stream>>>(eidx + E, H, E);
        scan_wg_kernel<<<NB, TB, 0, stream>>>(H, totals, nwg);
        scan_bucket_kernel<<<1, 1024, 0, stream>>>(totals, basep, base2, E);
        place_kernel<<<nwg, TB, 0, stream>>>(eidx, eidx + E, probs, H, totals, basep,
                                             sorted_idx, sorted_q, E, nwg);
        node_sort_kernel<<<NB, TB, 0, stream>>>(basep, totals, sorted_idx, sorted_q,
                                                sorted2, base2);
        size_t threads = (size_t)N_NODES * 64;
        gather2_kernel<<<(int)((threads + 255) / 256), 256, 0, stream>>>(
            x, xh, weight, slw, base2, sorted2, out);
    } else {
        const int T = 256;
        hipMemsetAsync(d_out, 0, (size_t)out_size * sizeof(float), stream);
        diffusion_scatter_kernel<<<(E + T - 1) / T, T, 0, stream>>>(
            x, eidx, eidx + E, probs, weight, out, E);
        int n4 = out_size / 4;
        diffusion_finalize_kernel<<<(n4 + T - 1) / T, T, 0, stream>>>(
            x, slw, out, n4);
    }
}

// Round 10
// 83.820 us; speedup vs baseline: 4.2759x; 1.1058x over previous
//
#include <hip/hip_runtime.h>
#include <hip/hip_fp16.h>

#define N_NODES 100000
#define DIM 16
#define BSHIFT 7
#define BNODES 128                                  // nodes per bucket
#define NB ((N_NODES + BNODES - 1) / BNODES)        // 782 buckets
#define TB 512
#define CHUNK 8192                                  // edges per place/hist wg
#define CAPB 4608                                   // sort_gather LDS tile capacity (mean 4092 + 8 sigma)
#define QSCALE 32767.0f

// ---------------- two-level bucket sort + fused node-sort/gather ----------------

// X: convert x (f32) to fp16 once; 8 floats -> 16B per thread.
__global__ __launch_bounds__(256) void convert_x_kernel(const float* __restrict__ x,
                                                        __half* __restrict__ xh,
                                                        int n8) {
    int i = blockIdx.x * 256 + threadIdx.x;
    if (i >= n8) return;
    float4 a = ((const float4*)x)[2 * i];
    float4 b = ((const float4*)x)[2 * i + 1];
    __half2 h0 = __floats2half2_rn(a.x, a.y);
    __half2 h1 = __floats2half2_rn(a.z, a.w);
    __half2 h2 = __floats2half2_rn(b.x, b.y);
    __half2 h3 = __floats2half2_rn(b.z, b.w);
    uint4 u;
    u.x = *reinterpret_cast<unsigned*>(&h0);
    u.y = *reinterpret_cast<unsigned*>(&h1);
    u.z = *reinterpret_cast<unsigned*>(&h2);
    u.w = *reinterpret_cast<unsigned*>(&h3);
    ((uint4*)xh)[i] = u;
}

// A: per-workgroup histogram of dst-buckets (LDS atomics only).
__global__ __launch_bounds__(TB) void hist_kernel(const int* __restrict__ dst,
                                                  unsigned* __restrict__ H,
                                                  int E) {
    __shared__ unsigned hist[NB];
    int tid = threadIdx.x;
    for (int i = tid; i < NB; i += TB) hist[i] = 0;
    __syncthreads();
    int e0 = blockIdx.x * CHUNK;
    int e1 = min(e0 + CHUNK, E);
    for (int e = e0 + tid; e < e1; e += TB)
        atomicAdd(&hist[((unsigned)dst[e]) >> BSHIFT], 1u);
    __syncthreads();
    unsigned* row = H + (size_t)blockIdx.x * NB;
    for (int i = tid; i < NB; i += TB) row[i] = hist[i];
}

// Block-wide exclusive scan (nthreads threads, multiple of 64, <=1024).
__device__ inline unsigned block_scan_excl(unsigned v, int tid, int nthreads,
                                           unsigned* warp_lds, unsigned* total_out) {
    unsigned x = v;
#pragma unroll
    for (int off = 1; off < 64; off <<= 1) {
        unsigned y = __shfl_up(x, off);
        if ((tid & 63) >= off) x += y;
    }
    int wid = tid >> 6;
    int nw = nthreads >> 6;
    if ((tid & 63) == 63) warp_lds[wid] = x;
    __syncthreads();
    if (tid < nw) {
        unsigned w = warp_lds[tid];
#pragma unroll
        for (int off = 1; off < 16; off <<= 1) {
            unsigned y = __shfl_up(w, off);
            if (tid >= off) w += y;
        }
        warp_lds[tid] = w;   // inclusive per-wave totals
    }
    __syncthreads();
    unsigned wbase = (wid > 0) ? warp_lds[wid - 1] : 0u;
    unsigned incl = x + wbase;
    if (total_out && tid == nthreads - 1) *total_out = incl;
    return incl - v;
}

// B1: for each bucket b, exclusive scan of H[wg][b] over wgs (in place) + total.
__global__ __launch_bounds__(TB) void scan_wg_kernel(unsigned* __restrict__ H,
                                                     unsigned* __restrict__ totals,
                                                     int nwg) {
    __shared__ unsigned warp_lds[16];
    int b = blockIdx.x;
    int tid = threadIdx.x;
    unsigned v = (tid < nwg) ? H[(size_t)tid * NB + b] : 0u;
    unsigned excl = block_scan_excl(v, tid, TB, warp_lds, &totals[b]);
    if (tid < nwg) H[(size_t)tid * NB + b] = excl;
}

// B2: exclusive scan of bucket totals -> bucket base offsets.
__global__ __launch_bounds__(1024) void scan_bucket_kernel(const unsigned* __restrict__ totals,
                                                           unsigned* __restrict__ base) {
    __shared__ unsigned warp_lds[16];
    int tid = threadIdx.x;
    unsigned v = (tid < NB) ? totals[tid] : 0u;
    unsigned excl = block_scan_excl(v, tid, 1024, warp_lds, nullptr);
    if (tid < NB) base[tid] = excl;
}

// C: LDS counting sort of the wg's chunk into (u8 dloc key, u32 src<<15|q15
// payload). Chunk counts derived by diffing adjacent scanned H rows.
// Writeout: 16 lanes per bucket, 4 buckets per wave, coalesced runs.
__global__ __launch_bounds__(TB) void place_kernel(const int* __restrict__ src,
                                                   const int* __restrict__ dst,
                                                   const float* __restrict__ probs,
                                                   const unsigned* __restrict__ O,
                                                   const unsigned* __restrict__ totals,
                                                   const unsigned* __restrict__ base,
                                                   unsigned char* __restrict__ key,
                                                   unsigned* __restrict__ payload,
                                                   int E, int nwg) {
    __shared__ unsigned recs_pl[CHUNK];           // 32 KB
    __shared__ unsigned char recs_k[CHUNK];       // 8 KB
    __shared__ unsigned lstart[NB];
    __shared__ unsigned lcur[NB];
    __shared__ unsigned gdst[NB];
    __shared__ unsigned warp_lds[16];
    int tid = threadIdx.x;
    int wg = blockIdx.x;
    int e0 = wg * CHUNK;
    int e1 = min(e0 + CHUNK, E);
    bool last = (wg == nwg - 1);

    // per-chunk counts = H[wg+1] - H[wg] (last: totals - H[wg]); gdst = base + H[wg]
    const unsigned* row  = O + (size_t)wg * NB;
    const unsigned* rown = O + (size_t)(wg + 1) * NB;
    for (int i = tid; i < NB; i += TB) {
        unsigned h = row[i];
        unsigned hn = last ? totals[i] : rown[i];
        gdst[i] = base[i] + h;
        lcur[i] = hn - h;                  // count for this wg
    }
    __syncthreads();

    // scan 782 bins, 2 per thread
    int b0 = 2 * tid, b1 = 2 * tid + 1;
    unsigned c0 = (b0 < NB) ? lcur[b0] : 0u;
    unsigned c1 = (b1 < NB) ? lcur[b1] : 0u;
    unsigned excl = block_scan_excl(c0 + c1, tid, TB, warp_lds, nullptr);
    __syncthreads();
    if (b0 < NB) { lstart[b0] = excl;      lcur[b0] = excl; }
    if (b1 < NB) { lstart[b1] = excl + c0; lcur[b1] = excl + c0; }
    __syncthreads();

    // place records into LDS, bucket-sorted
    for (int e = e0 + tid; e < e1; e += TB) {
        unsigned d = (unsigned)dst[e];
        unsigned s = (unsigned)src[e];
        float p = probs[e];
        unsigned b = d >> BSHIFT;
        unsigned pos = atomicAdd(&lcur[b], 1u);
        unsigned q = __float2uint_rn(p * QSCALE);
        recs_pl[pos] = (s << 15) | q;                 // src 17b | q 15b
        recs_k[pos] = (unsigned char)(d & (BNODES - 1));
    }
    __syncthreads();

    // writeout: 16 lanes per bucket, 4 buckets per wave (runs avg ~10 recs)
    int wv = tid >> 6, ln = tid & 63;
    int bq = ln >> 4, ln16 = ln & 15;
    for (int bb = wv * 4; bb < NB; bb += (TB >> 6) * 4) {
        int b = bb + bq;
        unsigned st = 0, cnt = 0, g = 0;
        if (b < NB) { st = lstart[b]; cnt = lcur[b] - st; g = gdst[b]; }
        for (unsigned k = ln16; k < cnt; k += 16) {
            payload[g + k] = recs_pl[st + k];
            key[g + k]     = recs_k[st + k];
        }
    }
}

// D (fused): one wg per bucket. Per CAPB-tile: node-histogram (u8 key reads),
// wave-0 scan, scatter payloads node-sorted into LDS, then 8 waves gather —
// 8 lanes/edge, 4-deep pipeline over each node's LDS segment, fp16 x-gather
// (L2-resident), f32 accumulate into LDS accs. Fused self-loop+clip epilogue.
__global__ __launch_bounds__(TB) void sort_gather_kernel(const float* __restrict__ x,
                                                         const __half* __restrict__ xh,
                                                         const float* __restrict__ weight,
                                                         const float* __restrict__ slw,
                                                         const unsigned* __restrict__ base,
                                                         const unsigned* __restrict__ totals,
                                                         const unsigned char* __restrict__ key,
                                                         const unsigned* __restrict__ payload,
                                                         float* __restrict__ out) {
    __shared__ unsigned buf[CAPB];                // 18.4 KB
    __shared__ float accs[BNODES * DIM];          // 8 KB
    __shared__ unsigned ncnt[BNODES];
    __shared__ unsigned nstart[BNODES];
    __shared__ unsigned ncur[BNODES];
    int tid = threadIdx.x;
    int b = blockIdx.x;
    unsigned s0 = base[b];
    unsigned cnt = totals[b];
    int wv = tid >> 6, lane = tid & 63;
    int sub = lane >> 3, dc = lane & 7;
    const __half2* xh2 = (const __half2*)xh;
    const float QS = 1.0f / QSCALE;

    for (int i = tid; i < BNODES * DIM; i += TB) accs[i] = 0.0f;

    for (unsigned t0 = 0; t0 < cnt; t0 += CAPB) {
        unsigned tcnt = min((unsigned)CAPB, cnt - t0);
        unsigned g0 = s0 + t0;
        if (tid < BNODES) ncnt[tid] = 0;
        __syncthreads();
        for (unsigned i = tid; i < tcnt; i += TB)
            atomicAdd(&ncnt[key[g0 + i]], 1u);
        __syncthreads();
        if (tid < 64) {   // exclusive scan of 128 bins, 2 per lane
            unsigned c0 = ncnt[2 * tid], c1 = ncnt[2 * tid + 1];
            unsigned v = c0 + c1;
            unsigned xs = v;
#pragma unroll
            for (int off = 1; off < 64; off <<= 1) {
                unsigned y = __shfl_up(xs, off);
                if (tid >= off) xs += y;
            }
            nstart[2 * tid]     = xs - v;  ncur[2 * tid]     = xs - v;
            nstart[2 * tid + 1] = xs - c1; ncur[2 * tid + 1] = xs - c1;
        }
        __syncthreads();
        for (unsigned i = tid; i < tcnt; i += TB) {
            unsigned k = key[g0 + i];
            unsigned pos = atomicAdd(&ncur[k], 1u);
            buf[pos] = payload[g0 + i];
        }
        __syncthreads();
        // gather: wave wv handles nodes wv, wv+8, ... (16 nodes per wave)
        for (int nloc = wv; nloc < BNODES; nloc += (TB >> 6)) {
            unsigned lo = nstart[nloc];
            unsigned hi = lo + ncnt[nloc];
            float ax = 0.0f, ay = 0.0f;
            for (unsigned i = lo + (unsigned)sub; i < hi; i += 32) {
                unsigned r0 = buf[i];
                unsigned r1 = (i + 8  < hi) ? buf[i + 8]  : 0u;
                unsigned r2 = (i + 16 < hi) ? buf[i + 16] : 0u;
                unsigned r3 = (i + 24 < hi) ? buf[i + 24] : 0u;
                float2 f0 = __half22float2(xh2[(size_t)(r0 >> 15) * 8 + dc]);
                float2 f1 = __half22float2(xh2[(size_t)(r1 >> 15) * 8 + dc]);
                float2 f2 = __half22float2(xh2[(size_t)(r2 >> 15) * 8 + dc]);
                float2 f3 = __half22float2(xh2[(size_t)(r3 >> 15) * 8 + dc]);
                float p0 = (float)(r0 & 0x7FFFu) * QS;
                float p1 = (float)(r1 & 0x7FFFu) * QS;
                float p2 = (float)(r2 & 0x7FFFu) * QS;
                float p3 = (float)(r3 & 0x7FFFu) * QS;
                ax = fmaf(f0.x, p0, ax); ay = fmaf(f0.y, p0, ay);
                ax = fmaf(f1.x, p1, ax); ay = fmaf(f1.y, p1, ay);
                ax = fmaf(f2.x, p2, ax); ay = fmaf(f2.y, p2, ay);
                ax = fmaf(f3.x, p3, ax); ay = fmaf(f3.y, p3, ay);
            }
            ax += __shfl_xor(ax, 8);  ay += __shfl_xor(ay, 8);
            ax += __shfl_xor(ax, 16); ay += __shfl_xor(ay, 16);
            ax += __shfl_xor(ax, 32); ay += __shfl_xor(ay, 32);
            if (lane < 8) {   // owner-exclusive: one wave per node
                float2* a2 = (float2*)&accs[nloc * DIM + 2 * dc];
                float2 cur = *a2;
                cur.x += ax; cur.y += ay;
                *a2 = cur;
            }
        }
        __syncthreads();   // protect ncnt/buf before next tile
    }

    // epilogue: out = clip(x*(1+slw) + accs*weight, 0, 1)
    float sc = 1.0f + slw[0];
    for (int idx = tid; idx < BNODES * 8; idx += TB) {
        int nloc = idx >> 3, q = idx & 7;
        int n = b * BNODES + nloc;
        if (n >= N_NODES) continue;
        float2 a = ((float2*)accs)[nloc * 8 + q];
        float2 xv = ((const float2*)x)[(size_t)n * 8 + q];
        float2 wv2 = ((const float2*)weight)[q];
        float2 r;
        r.x = fminf(fmaxf(fmaf(xv.x, sc, a.x * wv2.x), 0.0f), 1.0f);
        r.y = fminf(fmaxf(fmaf(xv.y, sc, a.y * wv2.y), 0.0f), 1.0f);
        ((float2*)out)[(size_t)n * 8 + q] = r;
    }
}

// ---------------- fallback path (R1): direct float atomics ----------------

__global__ void diffusion_scatter_kernel(const float* __restrict__ x,
                                         const int* __restrict__ src,
                                         const int* __restrict__ dst,
                                         const float* __restrict__ probs,
                                         const float* __restrict__ weight,
                                         float* __restrict__ acc,
                                         int E) {
    int e = blockIdx.x * blockDim.x + threadIdx.x;
    if (e >= E) return;
    int s = src[e];
    int d = dst[e];
    float p = probs[e];
    const float4* xs = reinterpret_cast<const float4*>(x + (size_t)s * DIM);
    const float4* w4 = reinterpret_cast<const float4*>(weight);
    float* outp = acc + (size_t)d * DIM;
#pragma unroll
    for (int q = 0; q < 4; ++q) {
        float4 xv = xs[q];
        float4 wv = w4[q];
        atomicAdd(&outp[q * 4 + 0], xv.x * p * wv.x);
        atomicAdd(&outp[q * 4 + 1], xv.y * p * wv.y);
        atomicAdd(&outp[q * 4 + 2], xv.z * p * wv.z);
        atomicAdd(&outp[q * 4 + 3], xv.w * p * wv.w);
    }
}

__global__ void diffusion_finalize_kernel(const float* __restrict__ x,
                                          const float* __restrict__ slw,
                                          float* __restrict__ out,
                                          int n4) {
    int i = blockIdx.x * blockDim.x + threadIdx.x;
    if (i >= n4) return;
    float s = 1.0f + slw[0];
    float4 xv = reinterpret_cast<const float4*>(x)[i];
    float4 a = reinterpret_cast<float4*>(out)[i];
    float4 r;
    r.x = fminf(fmaxf(fmaf(xv.x, s, a.x), 0.0f), 1.0f);
    r.y = fminf(fmaxf(fmaf(xv.y, s, a.y), 0.0f), 1.0f);
    r.z = fminf(fmaxf(fmaf(xv.z, s, a.z), 0.0f), 1.0f);
    r.w = fminf(fmaxf(fmaf(xv.w, s, a.w), 0.0f), 1.0f);
    reinterpret_cast<float4*>(out)[i] = r;
}

extern "C" void kernel_launch(void* const* d_in, const int* in_sizes, int n_in,
                              void* d_out, int out_size, void* d_ws, size_t ws_size,
                              hipStream_t stream) {
    const float* x      = (const float*)d_in[0];
    const int*   eidx   = (const int*)d_in[1];   // [2, E]: row0=src, row1=dst
    const float* probs  = (const float*)d_in[2];
    const float* weight = (const float*)d_in[3];
    const float* slw    = (const float*)d_in[4];

    int E = in_sizes[2];
    float* out = (float*)d_out;

    int nwg = (E + CHUNK - 1) / CHUNK;   // 391 for E=3.2M

    // ws layout (16B-aligned segments):
    // H[nwg*NB] u32 | totals[NB] | base[NB] | xh[N*DIM] fp16 |
    // key[E] u8 | payload[E] u32
    size_t off = 0;
    auto alloc = [&](size_t bytes) { size_t o = off; off += (bytes + 15) & ~(size_t)15; return o; };
    size_t o_H       = alloc((size_t)nwg * NB * 4);
    size_t o_totals  = alloc((size_t)NB * 4);
    size_t o_base    = alloc((size_t)NB * 4);
    size_t o_xh      = alloc((size_t)N_NODES * DIM * 2);
    size_t o_key     = alloc((size_t)E);
    size_t o_payload = alloc((size_t)E * 4);
    size_t need = off;

    if (ws_size >= need && nwg <= TB) {
        char* ws = (char*)d_ws;
        unsigned* H           = (unsigned*)(ws + o_H);
        unsigned* totals      = (unsigned*)(ws + o_totals);
        unsigned* basep       = (unsigned*)(ws + o_base);
        __half*   xh          = (__half*)(ws + o_xh);
        unsigned char* key    = (unsigned char*)(ws + o_key);
        unsigned* payload     = (unsigned*)(ws + o_payload);

        int n8 = N_NODES * DIM / 8;
        convert_x_kernel<<<(n8 + 255) / 256, 256, 0, stream>>>(x, xh, n8);
        hist_kernel<<<nwg, TB, 0, stream>>>(eidx + E, H, E);
        scan_wg_kernel<<<NB, TB, 0, stream>>>(H, totals, nwg);
        scan_bucket_kernel<<<1, 1024, 0, stream>>>(totals, basep);
        place_kernel<<<nwg, TB, 0, stream>>>(eidx, eidx + E, probs, H, totals, basep,
                                             key, payload, E, nwg);
        sort_gather_kernel<<<NB, TB, 0, stream>>>(x, xh, weight, slw, basep, totals,
                                                  key, payload, out);
    } else {
        const int T = 256;
        hipMemsetAsync(d_out, 0, (size_t)out_size * sizeof(float), stream);
        diffusion_scatter_kernel<<<(E + T - 1) / T, T, 0, stream>>>(
            x, eidx, eidx + E, probs, weight, out, E);
        int n4 = out_size / 4;
        diffusion_finalize_kernel<<<(n4 + T - 1) / T, T, 0, stream>>>(
            x, slw, out, n4);
    }
}